// Round 5
// baseline (899.102 us; speedup 1.0000x reference)
//
#include <hip/hip_runtime.h>

#define N_CHR 50000
#define E_CHR 500000
#define N_SLV 30000
#define E_SLV 300000
#define BATCH_B 256
#define FEAT 64
#define DIM 128
#define HALF 64
#define ENSN 3
#define CB_CHR ((N_CHR + 255) / 256)   // 196 coarse buckets (chr)
#define CB_SLV ((N_SLV + 255) / 256)   // 118 coarse buckets (slv)
#define CB_TOT (CB_CHR + CB_SLV)       // 314

typedef unsigned int u32;
typedef unsigned short u16;
typedef __attribute__((ext_vector_type(8))) short short8;
typedef __attribute__((ext_vector_type(4))) float floatx4;
typedef __attribute__((ext_vector_type(2))) unsigned int u32x2;

// ---------------- bf16 helpers (round-to-nearest-even) ----------------

__device__ inline u16 f2b(float f) {
    u32 u = __builtin_bit_cast(u32, f);
    u += 0x7FFFu + ((u >> 16) & 1u);
    return (u16)(u >> 16);
}
__device__ inline float b2f_lo(u32 v) { return __builtin_bit_cast(float, v << 16); }
__device__ inline float b2f_hi(u32 v) { return __builtin_bit_cast(float, v & 0xFFFF0000u); }
__device__ inline u32 packb(float a, float b) { return (u32)f2b(a) | ((u32)f2b(b) << 16); }

// ---------------- input convert: fp32 -> bf16, both branches ----------------

__global__ void xconv_k(const float* __restrict__ xc, const float* __restrict__ xs,
                        u16* __restrict__ oc, u16* __restrict__ os) {
    const int nc = N_CHR * FEAT, ns = N_SLV * FEAT;
    int i = blockIdx.x * blockDim.x + threadIdx.x;
    int stride = gridDim.x * blockDim.x;
    for (; i < nc + ns; i += stride) {
        if (i < nc) oc[i] = f2b(xc[i]);
        else os[i - nc] = f2b(xs[i - nc]);
    }
}

// ---------------- weight convert+transpose: W[E][K][N] f32 -> Wt[E][N][K] bf16 ----------------

__global__ void wconv_k(const float* __restrict__ Wc, const float* __restrict__ Ws,
                        u16* __restrict__ Wtc, u16* __restrict__ Wts, int K, int N) {
    const float* W = blockIdx.z ? Ws : Wc;
    u16* Wt = blockIdx.z ? Wts : Wtc;
    int e = blockIdx.y;
    int idx = blockIdx.x * 256 + threadIdx.x;
    if (idx >= K * N) return;
    int k = idx / N, nn = idx - k * N;
    Wt[((size_t)e * N + nn) * K + k] = f2b(W[(size_t)e * K * N + idx]);
}

// ---------------- CSR build: bucketed counting sort ----------------
// pack: src | ((dst & 255) << 17)   (src < 2^17 for both graphs)

__global__ void coarse_hist_k(const int* __restrict__ cdst, const int* __restrict__ sdst,
                              int* __restrict__ cnt) {
    __shared__ int h[CB_TOT];
    int t = threadIdx.x;
    for (int i = t; i < CB_TOT; i += 256) h[i] = 0;
    __syncthreads();
    int i = blockIdx.x * 256 + t;
    int stride = gridDim.x * 256;
    for (; i < E_CHR + E_SLV; i += stride) {
        int bkt = (i < E_CHR) ? (cdst[i] >> 8) : (CB_CHR + (sdst[i - E_CHR] >> 8));
        atomicAdd(&h[bkt], 1);
    }
    __syncthreads();
    for (int j = t; j < CB_TOT; j += 256)
        if (h[j]) atomicAdd(&cnt[j], h[j]);
}

// single wave scans the 314 bucket counts -> coarse offsets + cursors
__global__ void coarse_scan_k(const int* __restrict__ cnt, int* __restrict__ off,
                              int* __restrict__ cur) {
    int t = threadIdx.x;           // 64 threads
    const int PER = (CB_TOT + 63) / 64;   // 5
    int loc[PER];
    int sum = 0;
    int s = t * PER;
#pragma unroll
    for (int k = 0; k < PER; k++) {
        int i = s + k;
        int v = (i < CB_TOT) ? cnt[i] : 0;
        loc[k] = sum;
        sum += v;
    }
    int inc = sum;
#pragma unroll
    for (int o = 1; o < 64; o <<= 1) {
        int sh = __shfl_up(inc, o, 64);
        if (t >= o) inc += sh;
    }
    int pre = inc - sum;
#pragma unroll
    for (int k = 0; k < PER; k++) {
        int i = s + k;
        if (i < CB_TOT) {
            off[i] = pre + loc[k];
            cur[i] = pre + loc[k];
        }
    }
    if (t == 63) off[CB_TOT] = inc;
}

__global__ void scatter_k(const int* __restrict__ cei, const int* __restrict__ sei,
                          int* __restrict__ cur, u32* __restrict__ staging) {
    int i = blockIdx.x * 256 + threadIdx.x;
    int stride = gridDim.x * 256;
    for (; i < E_CHR + E_SLV; i += stride) {
        int src, dst, bkt;
        if (i < E_CHR) {
            src = cei[i]; dst = cei[E_CHR + i]; bkt = dst >> 8;
        } else {
            int j = i - E_CHR;
            src = sei[j]; dst = sei[E_SLV + j]; bkt = CB_CHR + (dst >> 8);
        }
        int p = atomicAdd(&cur[bkt], 1);
        staging[p] = (u32)src | ((u32)(dst & 255) << 17);
    }
}

__device__ inline int block_exscan(int v) {
    int lane = threadIdx.x & 63, wv = threadIdx.x >> 6;
    int inc = v;
#pragma unroll
    for (int o = 1; o < 64; o <<= 1) {
        int t = __shfl_up(inc, o, 64);
        if (lane >= o) inc += t;
    }
    __shared__ int ws[4];
    if (lane == 63) ws[wv] = inc;
    __syncthreads();
    if (threadIdx.x == 0) {
        int c = 0;
#pragma unroll
        for (int k = 0; k < 4; k++) { int t = ws[k]; ws[k] = c; c += t; }
    }
    __syncthreads();
    int r = ws[wv] + inc - v;
    __syncthreads();
    return r;
}

// one block per coarse bucket: counting sort over the 256 node slots
__global__ __launch_bounds__(256) void bucket_sort_k(
        const u32* __restrict__ staging, const int* __restrict__ coff,
        int* __restrict__ off_c, int* __restrict__ off_s,
        int* __restrict__ csr_c, int* __restrict__ csr_s) {
    int b = blockIdx.x, t = threadIdx.x;
    int isS = b >= CB_CHR;
    int base = coff[b], end = coff[b + 1];
    int n = isS ? N_SLV : N_CHR;
    int* off = isS ? off_s : off_c;
    int* csr = isS ? csr_s : csr_c;
    int outBase = isS ? base - E_CHR : base;
    int nodeBase = (isS ? (b - CB_CHR) : b) << 8;
    __shared__ int hist[256];
    __shared__ int cur[256];
    hist[t] = 0;
    __syncthreads();
    for (int i = base + t; i < end; i += 256)
        atomicAdd(&hist[staging[i] >> 17], 1);
    __syncthreads();
    int p = block_exscan(hist[t]);
    int node = nodeBase + t;
    if (node <= n) off[node] = outBase + p;
    cur[t] = p;
    __syncthreads();
    for (int i = base + t; i < end; i += 256) {
        u32 v = staging[i];
        int pos = atomicAdd(&cur[v >> 17], 1);
        csr[outBase + pos] = (int)(v & 0x1FFFFu);
    }
}

// per-graph node ranges from SORTED batch vectors
__global__ void bounds_both_k(const int* __restrict__ cb, const int* __restrict__ sb,
                              int* __restrict__ start_c, int* __restrict__ start_s) {
    int t = threadIdx.x + blockIdx.x * blockDim.x;
    int isS = t >= 320;
    int b = isS ? t - 320 : t;
    if (b > BATCH_B) return;
    const int* batch = isS ? sb : cb;
    int n = isS ? N_SLV : N_CHR;
    int* start = isS ? start_s : start_c;
    if (b == BATCH_B) { start[b] = n; return; }
    int lo = 0, hi = n;
    while (lo < hi) {
        int mid = (lo + hi) >> 1;
        if (batch[mid] < b) lo = mid + 1; else hi = mid;
    }
    start[b] = lo;
}

// ---------------- layer-1 aggregation: bf16 in/out, z = branch, 8 nodes/block ----------------

__global__ __launch_bounds__(256) void agg1_k(
        const u16* __restrict__ Xc, const int* __restrict__ offc, const int* __restrict__ csrc,
        u16* __restrict__ Yc, int nc,
        const u16* __restrict__ Xs, const int* __restrict__ offs, const int* __restrict__ csrs,
        u16* __restrict__ Ys, int ns) {
    int z = blockIdx.z;
    const u32* X32 = (const u32*)(z ? Xs : Xc);
    const int* off = z ? offs : offc;
    const int* csr = z ? csrs : csrc;
    u32* Y32 = (u32*)(z ? Ys : Yc);
    int n = z ? ns : nc;
    int i = blockIdx.x * 8 + (threadIdx.x >> 5);
    if (i >= n) return;
    int fp = threadIdx.x & 31;
    int s = off[i], e2 = off[i + 1];
    float a0 = 0.f, a1 = 0.f;
    int j = s;
    for (; j + 3 < e2; j += 4) {
        u32 v0 = X32[(size_t)csr[j] * 32 + fp];
        u32 v1 = X32[(size_t)csr[j + 1] * 32 + fp];
        u32 v2 = X32[(size_t)csr[j + 2] * 32 + fp];
        u32 v3 = X32[(size_t)csr[j + 3] * 32 + fp];
        a0 += b2f_lo(v0) + b2f_lo(v1) + b2f_lo(v2) + b2f_lo(v3);
        a1 += b2f_hi(v0) + b2f_hi(v1) + b2f_hi(v2) + b2f_hi(v3);
    }
    for (; j < e2; j++) {
        u32 v = X32[(size_t)csr[j] * 32 + fp];
        a0 += b2f_lo(v); a1 += b2f_hi(v);
    }
    Y32[(size_t)i * 32 + fp] = packb(a0, a1);
}

// ---------------- bf16 aggregation F=128, y = ens, z = branch, 8 nodes/block ----------------

template<bool RELU>
__global__ __launch_bounds__(256) void aggb128_k(
        const u16* __restrict__ Hc, const int* __restrict__ offc, const int* __restrict__ csrc,
        u16* __restrict__ Yc, int nc,
        const u16* __restrict__ Hs, const int* __restrict__ offs, const int* __restrict__ csrs,
        u16* __restrict__ Ys, int ns) {
    int z = blockIdx.z, e = blockIdx.y;
    int n = z ? ns : nc;
    const int* off = z ? offs : offc;
    const int* csr = z ? csrs : csrc;
    const u32* He = (const u32*)((z ? Hs : Hc) + (size_t)e * n * DIM);
    u32* Ye = (u32*)((z ? Ys : Yc) + (size_t)e * n * DIM);
    int i = blockIdx.x * 8 + (threadIdx.x >> 5);
    if (i >= n) return;
    int fp = threadIdx.x & 31;
    int s = off[i], e2 = off[i + 1];
    float a0 = 0.f, a1 = 0.f, a2 = 0.f, a3 = 0.f;
    int j = s;
    for (; j + 3 < e2; j += 4) {
        u32x2 v0 = *(const u32x2*)(He + (size_t)csr[j] * 64 + fp * 2);
        u32x2 v1 = *(const u32x2*)(He + (size_t)csr[j + 1] * 64 + fp * 2);
        u32x2 v2 = *(const u32x2*)(He + (size_t)csr[j + 2] * 64 + fp * 2);
        u32x2 v3 = *(const u32x2*)(He + (size_t)csr[j + 3] * 64 + fp * 2);
        a0 += b2f_lo(v0.x) + b2f_lo(v1.x) + b2f_lo(v2.x) + b2f_lo(v3.x);
        a1 += b2f_hi(v0.x) + b2f_hi(v1.x) + b2f_hi(v2.x) + b2f_hi(v3.x);
        a2 += b2f_lo(v0.y) + b2f_lo(v1.y) + b2f_lo(v2.y) + b2f_lo(v3.y);
        a3 += b2f_hi(v0.y) + b2f_hi(v1.y) + b2f_hi(v2.y) + b2f_hi(v3.y);
    }
    for (; j < e2; j++) {
        u32x2 v = *(const u32x2*)(He + (size_t)csr[j] * 64 + fp * 2);
        a0 += b2f_lo(v.x); a1 += b2f_hi(v.x);
        a2 += b2f_lo(v.y); a3 += b2f_hi(v.y);
    }
    if (RELU) {
        a0 = fmaxf(a0, 0.f); a1 = fmaxf(a1, 0.f);
        a2 = fmaxf(a2, 0.f); a3 = fmaxf(a3, 0.f);
    }
    u32x2 o; o.x = packb(a0, a1); o.y = packb(a2, a3);
    *(u32x2*)(Ye + (size_t)i * 64 + fp * 2) = o;
}

// ---------------- bf16 aggregation F=64, y = ens, z = branch, 16 nodes/block ----------------

template<bool RELU>
__global__ __launch_bounds__(256) void aggb64_k(
        const u16* __restrict__ Hc, const int* __restrict__ offc, const int* __restrict__ csrc,
        u16* __restrict__ Yc, int nc,
        const u16* __restrict__ Hs, const int* __restrict__ offs, const int* __restrict__ csrs,
        u16* __restrict__ Ys, int ns) {
    int z = blockIdx.z, e = blockIdx.y;
    int n = z ? ns : nc;
    const int* off = z ? offs : offc;
    const int* csr = z ? csrs : csrc;
    const u32* He = (const u32*)((z ? Hs : Hc) + (size_t)e * n * HALF);
    u32* Ye = (u32*)((z ? Ys : Yc) + (size_t)e * n * HALF);
    int i = blockIdx.x * 16 + (threadIdx.x >> 4);
    if (i >= n) return;
    int fp = threadIdx.x & 15;
    int s = off[i], e2 = off[i + 1];
    float a0 = 0.f, a1 = 0.f, a2 = 0.f, a3 = 0.f;
    int j = s;
    for (; j + 3 < e2; j += 4) {
        u32x2 v0 = *(const u32x2*)(He + (size_t)csr[j] * 32 + fp * 2);
        u32x2 v1 = *(const u32x2*)(He + (size_t)csr[j + 1] * 32 + fp * 2);
        u32x2 v2 = *(const u32x2*)(He + (size_t)csr[j + 2] * 32 + fp * 2);
        u32x2 v3 = *(const u32x2*)(He + (size_t)csr[j + 3] * 32 + fp * 2);
        a0 += b2f_lo(v0.x) + b2f_lo(v1.x) + b2f_lo(v2.x) + b2f_lo(v3.x);
        a1 += b2f_hi(v0.x) + b2f_hi(v1.x) + b2f_hi(v2.x) + b2f_hi(v3.x);
        a2 += b2f_lo(v0.y) + b2f_lo(v1.y) + b2f_lo(v2.y) + b2f_lo(v3.y);
        a3 += b2f_hi(v0.y) + b2f_hi(v1.y) + b2f_hi(v2.y) + b2f_hi(v3.y);
    }
    for (; j < e2; j++) {
        u32x2 v = *(const u32x2*)(He + (size_t)csr[j] * 32 + fp * 2);
        a0 += b2f_lo(v.x); a1 += b2f_hi(v.x);
        a2 += b2f_lo(v.y); a3 += b2f_hi(v.y);
    }
    if (RELU) {
        a0 = fmaxf(a0, 0.f); a1 = fmaxf(a1, 0.f);
        a2 = fmaxf(a2, 0.f); a3 = fmaxf(a3, 0.f);
    }
    u32x2 o; o.x = packb(a0, a1); o.y = packb(a2, a3);
    *(u32x2*)(Ye + (size_t)i * 32 + fp * 2) = o;
}

// ---------------- MFMA GEMM, LDS-staged weights, y = ens, z = branch ----------------
// A[m=lane&15][k=quad*8+j]; B from Wt rows; C/D col=lane&15, row=quad*4+reg.

#define WPAD 8

template<int K, int COLS, bool RELU>
__global__ __launch_bounds__(256) void gemm_mfma_k(
        const u16* __restrict__ Xc, size_t esc, const u16* __restrict__ Wtc,
        u16* __restrict__ Yc, int nc,
        const u16* __restrict__ Xs, size_t ess, const u16* __restrict__ Wts,
        u16* __restrict__ Ys, int ns) {
    __shared__ u16 wlds[COLS * (K + WPAD)];
    const int z = blockIdx.z, e = blockIdx.y;
    const int n = z ? ns : nc;
    const u16* Xe = (z ? Xs : Xc) + (size_t)e * (z ? ess : esc);
    const u16* We = (z ? Wts : Wtc) + (size_t)e * COLS * K;
    u16* Ye = (z ? Ys : Yc) + (size_t)e * (size_t)n * COLS;
    for (int c = threadIdx.x; c < COLS * (K / 8); c += 256) {
        int row = c / (K / 8), seg = c - row * (K / 8);
        *(short8*)(wlds + row * (K + WPAD) + seg * 8) = *(const short8*)(We + (size_t)row * K + seg * 8);
    }
    __syncthreads();
    int wave = threadIdx.x >> 6, lane = threadIdx.x & 63;
    int quad = lane >> 4, nq = lane & 15;
    int m0 = blockIdx.x * 256 + wave * 64;
    if (m0 >= n) return;
    constexpr int NT = COLS / 16, KT = K / 32;
    floatx4 acc[4][NT];
#pragma unroll
    for (int rg = 0; rg < 4; rg++)
#pragma unroll
        for (int t = 0; t < NT; t++) acc[rg][t] = (floatx4)(0.f);
#pragma unroll
    for (int kt = 0; kt < KT; kt++) {
        int k0 = kt * 32 + quad * 8;
        short8 a[4];
#pragma unroll
        for (int rg = 0; rg < 4; rg++) {
            int row = m0 + rg * 16 + nq;
            int rc = row < n ? row : n - 1;
            a[rg] = *(const short8*)(Xe + (size_t)rc * K + k0);
        }
#pragma unroll
        for (int t = 0; t < NT; t++) {
            short8 b = *(const short8*)(wlds + (t * 16 + nq) * (K + WPAD) + k0);
#pragma unroll
            for (int rg = 0; rg < 4; rg++)
                acc[rg][t] = __builtin_amdgcn_mfma_f32_16x16x32_bf16(a[rg], b, acc[rg][t], 0, 0, 0);
        }
    }
    int rbase = quad * 4;
#pragma unroll
    for (int rg = 0; rg < 4; rg++)
#pragma unroll
        for (int t = 0; t < NT; t++)
#pragma unroll
            for (int r = 0; r < 4; r++) {
                int row = m0 + rg * 16 + rbase + r;
                if (row < n) {
                    float v = acc[rg][t][r];
                    if (RELU) v = fmaxf(v, 0.f);
                    Ye[(size_t)row * COLS + t * 16 + nq] = f2b(v);
                }
            }
}

// ---------------- global_add_pool: 4 waves/block, u32 loads, LDS combine ----------------

__global__ __launch_bounds__(256) void pool_b_k(const u16* __restrict__ H,
                                                const int* __restrict__ start,
                                                float* __restrict__ rep, int n, int colOff) {
    int b = blockIdx.x, e = blockIdx.y;
    const u32* He = (const u32*)(H + (size_t)e * n * HALF);
    int t = threadIdx.x;
    int wave = t >> 6, lane = t & 63;
    int fp = lane & 31, rp = lane >> 5;
    int s = start[b], e2 = start[b + 1];
    float a0 = 0.f, a1 = 0.f;
    for (int i = s + wave * 2 + rp; i < e2; i += 8) {
        u32 v = He[(size_t)i * 32 + fp];
        a0 += b2f_lo(v); a1 += b2f_hi(v);
    }
    __shared__ float sm[8][32][2];
    sm[wave * 2 + rp][fp][0] = a0;
    sm[wave * 2 + rp][fp][1] = a1;
    __syncthreads();
    if (t < 64) {
        int f2 = t & 31, half = t >> 5;
        float acc = 0.f;
#pragma unroll
        for (int k = 0; k < 8; k++) acc += sm[k][f2][half];
        rep[b * (2 * ENSN * HALF) + colOff + e * HALF + f2 * 2 + half] = acc;
    }
}

// ---------------- projection heads -> hg[B, 2*ENS*DIM] (fp32) ----------------

__global__ void head_k(const float* __restrict__ rep,
                       const float* __restrict__ cW, const float* __restrict__ cB,
                       const float* __restrict__ sW, const float* __restrict__ sB,
                       float* __restrict__ hg) {
    int b = blockIdx.x;
    int be = blockIdx.y;
    int branch = be / ENSN, e = be % ENSN;
    int c = threadIdx.x;               // 128 threads
    __shared__ float r[HALF];
    const float* repRow = rep + b * (2 * ENSN * HALF) + branch * (ENSN * HALF) + e * HALF;
    if (c < HALF) r[c] = repRow[c];
    __syncthreads();
    const float* W = (branch ? sW : cW) + e * HALF * DIM;
    const float* Bv = (branch ? sB : cB) + e * DIM;
    float acc = Bv[c];
#pragma unroll
    for (int k = 0; k < HALF; k++) acc = fmaf(r[k], W[k * DIM + c], acc);
    hg[b * (2 * ENSN * DIM) + branch * (ENSN * DIM) + e * DIM + c] = fmaxf(acc, 0.f);
}

// ---------------- final MLP ----------------

__global__ void final_k(const float* __restrict__ hg, const float* __restrict__ W1,
                        const float* __restrict__ b1, const float* __restrict__ W2,
                        const float* __restrict__ b2, float* __restrict__ out) {
    int b = blockIdx.x;
    int c = threadIdx.x;               // 128 threads
    const int IN = 2 * ENSN * DIM;     // 768
    __shared__ float row[2 * ENSN * DIM];
    for (int i = c; i < IN; i += DIM) row[i] = hg[b * IN + i];
    __syncthreads();
    float acc = b1[c];
    for (int k = 0; k < IN; k++) acc = fmaf(row[k], W1[k * DIM + c], acc);
    acc = fmaxf(acc, 0.f);
    __shared__ float red[DIM];
    red[c] = acc * W2[c];
    __syncthreads();
    for (int s = DIM / 2; s > 0; s >>= 1) {
        if (c < s) red[c] += red[c + s];
        __syncthreads();
    }
    if (c == 0) out[b] = red[0] + b2[0];
}

// ---------------- host ----------------

extern "C" void kernel_launch(void* const* d_in, const int* in_sizes, int n_in,
                              void* d_out, int out_size, void* d_ws, size_t ws_size,
                              hipStream_t stream) {
    const float* chr_x = (const float*)d_in[0];
    const float* slv_x = (const float*)d_in[1];
    const int* chr_ei = (const int*)d_in[2];
    const int* slv_ei = (const int*)d_in[3];
    const int* chr_batch = (const int*)d_in[4];
    const int* slv_batch = (const int*)d_in[5];
    const float* chr_W0 = (const float*)d_in[6];
    const float* chr_W1 = (const float*)d_in[7];
    const float* chr_W2 = (const float*)d_in[8];
    const float* slv_W0 = (const float*)d_in[9];
    const float* slv_W1 = (const float*)d_in[10];
    const float* slv_W2 = (const float*)d_in[11];
    const float* cfc_W = (const float*)d_in[12];
    const float* cfc_b = (const float*)d_in[13];
    const float* sfc_W = (const float*)d_in[14];
    const float* sfc_b = (const float*)d_in[15];
    const float* fc1_W = (const float*)d_in[16];
    const float* fc1_b = (const float*)d_in[17];
    const float* fc2_W = (const float*)d_in[18];
    const float* fc2_b = (const float*)d_in[19];
    float* out = (float*)d_out;

    char* w = (char*)d_ws;
    auto carve = [&](size_t bytes) {
        void* p = (void*)w;
        w += (bytes + 255) & ~(size_t)255;
        return p;
    };
    int* off_chr = (int*)carve((N_CHR + 1) * sizeof(int));
    int* csr_chr = (int*)carve((size_t)E_CHR * sizeof(int));
    int* off_slv = (int*)carve((N_SLV + 1) * sizeof(int));
    int* csr_slv = (int*)carve((size_t)E_SLV * sizeof(int));
    int* ccnt    = (int*)carve(CB_TOT * sizeof(int));
    int* coff    = (int*)carve((CB_TOT + 1) * sizeof(int));
    int* ccur    = (int*)carve(CB_TOT * sizeof(int));
    u32* staging = (u32*)carve((size_t)(E_CHR + E_SLV) * sizeof(u32));
    int* start_chr = (int*)carve((BATCH_B + 1) * sizeof(int));
    int* start_slv = (int*)carve((BATCH_B + 1) * sizeof(int));
    u16* cW0t = (u16*)carve((size_t)ENSN * DIM * FEAT * sizeof(u16));
    u16* cW1t = (u16*)carve((size_t)ENSN * DIM * DIM * sizeof(u16));
    u16* cW2t = (u16*)carve((size_t)ENSN * HALF * DIM * sizeof(u16));
    u16* sW0t = (u16*)carve((size_t)ENSN * DIM * FEAT * sizeof(u16));
    u16* sW1t = (u16*)carve((size_t)ENSN * DIM * DIM * sizeof(u16));
    u16* sW2t = (u16*)carve((size_t)ENSN * HALF * DIM * sizeof(u16));
    u16* xb_chr = (u16*)carve((size_t)N_CHR * FEAT * sizeof(u16));
    u16* xb_slv = (u16*)carve((size_t)N_SLV * FEAT * sizeof(u16));
    float* rep = (float*)carve((size_t)BATCH_B * 2 * ENSN * HALF * sizeof(float));
    float* hg  = (float*)carve((size_t)BATCH_B * 2 * ENSN * DIM * sizeof(float));
    u16* aggX_c = (u16*)carve((size_t)N_CHR * FEAT * sizeof(u16));
    u16* bufP_c = (u16*)carve((size_t)ENSN * N_CHR * DIM * sizeof(u16));
    u16* bufQ_c = (u16*)carve((size_t)ENSN * N_CHR * DIM * sizeof(u16));
    // decide if the slv branch gets its own buffers (full z-merge) or reuses chr's
    size_t used = (size_t)(w - (char*)d_ws);
    size_t needS = (((size_t)N_SLV * FEAT * 2 + 255) & ~(size_t)255)
                 + 2 * (((size_t)ENSN * N_SLV * DIM * 2 + 255) & ~(size_t)255);
    bool merged = used + needS <= ws_size;
    u16* aggX_s = merged ? (u16*)carve((size_t)N_SLV * FEAT * sizeof(u16)) : aggX_c;
    u16* bufP_s = merged ? (u16*)carve((size_t)ENSN * N_SLV * DIM * sizeof(u16)) : bufP_c;
    u16* bufQ_s = merged ? (u16*)carve((size_t)ENSN * N_SLV * DIM * sizeof(u16)) : bufQ_c;

    // ---- converts ----
    xconv_k<<<512, 256, 0, stream>>>(chr_x, slv_x, xb_chr, xb_slv);
    wconv_k<<<dim3((FEAT * DIM + 255) / 256, ENSN, 2), 256, 0, stream>>>(chr_W0, slv_W0, cW0t, sW0t, FEAT, DIM);
    wconv_k<<<dim3((DIM * DIM + 255) / 256, ENSN, 2), 256, 0, stream>>>(chr_W1, slv_W1, cW1t, sW1t, DIM, DIM);
    wconv_k<<<dim3((DIM * HALF + 255) / 256, ENSN, 2), 256, 0, stream>>>(chr_W2, slv_W2, cW2t, sW2t, DIM, HALF);

    // ---- CSR build: bucketed counting sort ----
    hipMemsetAsync(ccnt, 0, CB_TOT * sizeof(int), stream);
    coarse_hist_k<<<256, 256, 0, stream>>>(chr_ei + E_CHR, slv_ei + E_SLV, ccnt);
    coarse_scan_k<<<1, 64, 0, stream>>>(ccnt, coff, ccur);
    scatter_k<<<256, 256, 0, stream>>>(chr_ei, slv_ei, ccur, staging);
    bucket_sort_k<<<CB_TOT, 256, 0, stream>>>(staging, coff, off_chr, off_slv, csr_chr, csr_slv);
    bounds_both_k<<<1, 640, 0, stream>>>(chr_batch, slv_batch, start_chr, start_slv);

    const int GX_GEMM_C = (N_CHR + 255) / 256;
    const int GX_GEMM_S = (N_SLV + 255) / 256;

    if (merged) {
        agg1_k<<<dim3((N_CHR + 7) / 8, 1, 2), 256, 0, stream>>>(
            xb_chr, off_chr, csr_chr, aggX_c, N_CHR,
            xb_slv, off_slv, csr_slv, aggX_s, N_SLV);
        gemm_mfma_k<FEAT, DIM, true><<<dim3(GX_GEMM_C, ENSN, 2), 256, 0, stream>>>(
            aggX_c, 0, cW0t, bufP_c, N_CHR, aggX_s, 0, sW0t, bufP_s, N_SLV);
        aggb128_k<false><<<dim3((N_CHR + 7) / 8, ENSN, 2), 256, 0, stream>>>(
            bufP_c, off_chr, csr_chr, bufQ_c, N_CHR,
            bufP_s, off_slv, csr_slv, bufQ_s, N_SLV);
        gemm_mfma_k<DIM, DIM, true><<<dim3(GX_GEMM_C, ENSN, 2), 256, 0, stream>>>(
            bufQ_c, (size_t)N_CHR * DIM, cW1t, bufP_c, N_CHR,
            bufQ_s, (size_t)N_SLV * DIM, sW1t, bufP_s, N_SLV);
        gemm_mfma_k<DIM, HALF, false><<<dim3(GX_GEMM_C, ENSN, 2), 256, 0, stream>>>(
            bufP_c, (size_t)N_CHR * DIM, cW2t, bufQ_c, N_CHR,
            bufP_s, (size_t)N_SLV * DIM, sW2t, bufQ_s, N_SLV);
        aggb64_k<true><<<dim3((N_CHR + 15) / 16, ENSN, 2), 256, 0, stream>>>(
            bufQ_c, off_chr, csr_chr, bufP_c, N_CHR,
            bufQ_s, off_slv, csr_slv, bufP_s, N_SLV);
        pool_b_k<<<dim3(BATCH_B, ENSN), 256, 0, stream>>>(bufP_c, start_chr, rep, N_CHR, 0);
        pool_b_k<<<dim3(BATCH_B, ENSN), 256, 0, stream>>>(bufP_s, start_slv, rep, N_SLV, ENSN * HALF);
    } else {
        // sequential fallback: reuse chr buffers for slv
        agg1_k<<<dim3((N_CHR + 7) / 8, 1, 1), 256, 0, stream>>>(
            xb_chr, off_chr, csr_chr, aggX_c, N_CHR, xb_chr, off_chr, csr_chr, aggX_c, N_CHR);
        gemm_mfma_k<FEAT, DIM, true><<<dim3(GX_GEMM_C, ENSN, 1), 256, 0, stream>>>(
            aggX_c, 0, cW0t, bufP_c, N_CHR, aggX_c, 0, cW0t, bufP_c, N_CHR);
        aggb128_k<false><<<dim3((N_CHR + 7) / 8, ENSN, 1), 256, 0, stream>>>(
            bufP_c, off_chr, csr_chr, bufQ_c, N_CHR, bufP_c, off_chr, csr_chr, bufQ_c, N_CHR);
        gemm_mfma_k<DIM, DIM, true><<<dim3(GX_GEMM_C, ENSN, 1), 256, 0, stream>>>(
            bufQ_c, (size_t)N_CHR * DIM, cW1t, bufP_c, N_CHR,
            bufQ_c, (size_t)N_CHR * DIM, cW1t, bufP_c, N_CHR);
        gemm_mfma_k<DIM, HALF, false><<<dim3(GX_GEMM_C, ENSN, 1), 256, 0, stream>>>(
            bufP_c, (size_t)N_CHR * DIM, cW2t, bufQ_c, N_CHR,
            bufP_c, (size_t)N_CHR * DIM, cW2t, bufQ_c, N_CHR);
        aggb64_k<true><<<dim3((N_CHR + 15) / 16, ENSN, 1), 256, 0, stream>>>(
            bufQ_c, off_chr, csr_chr, bufP_c, N_CHR, bufQ_c, off_chr, csr_chr, bufP_c, N_CHR);
        pool_b_k<<<dim3(BATCH_B, ENSN), 256, 0, stream>>>(bufP_c, start_chr, rep, N_CHR, 0);

        agg1_k<<<dim3((N_SLV + 7) / 8, 1, 1), 256, 0, stream>>>(
            xb_slv, off_slv, csr_slv, aggX_c, N_SLV, xb_slv, off_slv, csr_slv, aggX_c, N_SLV);
        gemm_mfma_k<FEAT, DIM, true><<<dim3(GX_GEMM_S, ENSN, 1), 256, 0, stream>>>(
            aggX_c, 0, sW0t, bufP_c, N_SLV, aggX_c, 0, sW0t, bufP_c, N_SLV);
        aggb128_k<false><<<dim3((N_SLV + 7) / 8, ENSN, 1), 256, 0, stream>>>(
            bufP_c, off_slv, csr_slv, bufQ_c, N_SLV, bufP_c, off_slv, csr_slv, bufQ_c, N_SLV);
        gemm_mfma_k<DIM, DIM, true><<<dim3(GX_GEMM_S, ENSN, 1), 256, 0, stream>>>(
            bufQ_c, (size_t)N_SLV * DIM, sW1t, bufP_c, N_SLV,
            bufQ_c, (size_t)N_SLV * DIM, sW1t, bufP_c, N_SLV);
        gemm_mfma_k<DIM, HALF, false><<<dim3(GX_GEMM_S, ENSN, 1), 256, 0, stream>>>(
            bufP_c, (size_t)N_SLV * DIM, sW2t, bufQ_c, N_SLV,
            bufP_c, (size_t)N_SLV * DIM, sW2t, bufQ_c, N_SLV);
        aggb64_k<true><<<dim3((N_SLV + 15) / 16, ENSN, 1), 256, 0, stream>>>(
            bufQ_c, off_slv, csr_slv, bufP_c, N_SLV, bufQ_c, off_slv, csr_slv, bufP_c, N_SLV);
        pool_b_k<<<dim3(BATCH_B, ENSN), 256, 0, stream>>>(bufP_c, start_slv, rep, N_SLV, ENSN * HALF);
    }

    // ---- heads + final MLP ----
    head_k<<<dim3(BATCH_B, 2 * ENSN), DIM, 0, stream>>>(rep, cfc_W, cfc_b, sfc_W, sfc_b, hg);
    final_k<<<BATCH_B, DIM, 0, stream>>>(hg, fc1_W, fc1_b, fc2_W, fc2_b, out);
}

// Round 6
// 456.468 us; speedup vs baseline: 1.9697x; 1.9697x over previous
//
#include <hip/hip_runtime.h>

#define N_CHR 50000
#define E_CHR 500000
#define N_SLV 30000
#define E_SLV 300000
#define E_TOT (E_CHR + E_SLV)
#define BATCH_B 256
#define FEAT 64
#define DIM 128
#define HALF 64
#define ENSN 3
#define CB_CHR ((N_CHR + 255) / 256)   // 196 coarse buckets (chr)
#define CB_SLV ((N_SLV + 255) / 256)   // 118 coarse buckets (slv)
#define CB_TOT (CB_CHR + CB_SLV)       // 314
#define NBLK 128                       // scatter blocks
#define CHUNK ((E_TOT + NBLK - 1) / NBLK)

typedef unsigned int u32;
typedef unsigned short u16;
typedef __attribute__((ext_vector_type(8))) short short8;
typedef __attribute__((ext_vector_type(4))) float floatx4;
typedef __attribute__((ext_vector_type(2))) unsigned int u32x2;

// ---------------- bf16 helpers (round-to-nearest-even) ----------------

__device__ inline u16 f2b(float f) {
    u32 u = __builtin_bit_cast(u32, f);
    u += 0x7FFFu + ((u >> 16) & 1u);
    return (u16)(u >> 16);
}
__device__ inline float b2f_lo(u32 v) { return __builtin_bit_cast(float, v << 16); }
__device__ inline float b2f_hi(u32 v) { return __builtin_bit_cast(float, v & 0xFFFF0000u); }
__device__ inline u32 packb(float a, float b) { return (u32)f2b(a) | ((u32)f2b(b) << 16); }

// ---------------- input convert: fp32 -> bf16, both branches ----------------

__global__ void xconv_k(const float* __restrict__ xc, const float* __restrict__ xs,
                        u16* __restrict__ oc, u16* __restrict__ os) {
    const int nc = N_CHR * FEAT, ns = N_SLV * FEAT;
    int i = blockIdx.x * blockDim.x + threadIdx.x;
    int stride = gridDim.x * blockDim.x;
    for (; i < nc + ns; i += stride) {
        if (i < nc) oc[i] = f2b(xc[i]);
        else os[i - nc] = f2b(xs[i - nc]);
    }
}

// ---------------- weight convert+transpose: W[E][K][N] f32 -> Wt[E][N][K] bf16 ----------------

__global__ void wconv_k(const float* __restrict__ Wc, const float* __restrict__ Ws,
                        u16* __restrict__ Wtc, u16* __restrict__ Wts, int K, int N) {
    const float* W = blockIdx.z ? Ws : Wc;
    u16* Wt = blockIdx.z ? Wts : Wtc;
    int e = blockIdx.y;
    int idx = blockIdx.x * 256 + threadIdx.x;
    if (idx >= K * N) return;
    int k = idx / N, nn = idx - k * N;
    Wt[((size_t)e * N + nn) * K + k] = f2b(W[(size_t)e * K * N + idx]);
}

// ---------------- CSR build: two-level bucketed counting sort ----------------
// pack: src | ((dst & 255) << 17)   (src < 2^17 for both graphs)

// phase A: per-block LDS histograms over 314 buckets; gh[bkt][blk]; btot via aggregated atomics
__global__ __launch_bounds__(256) void hist_blocks_k(
        const int* __restrict__ cdst, const int* __restrict__ sdst,
        int* __restrict__ gh, int* __restrict__ btot) {
    __shared__ int h[CB_TOT];
    int blk = blockIdx.x, t = threadIdx.x;
    for (int i = t; i < CB_TOT; i += 256) h[i] = 0;
    __syncthreads();
    int s = blk * CHUNK, e = s + CHUNK;
    if (e > E_TOT) e = E_TOT;
    for (int i = s + t; i < e; i += 256) {
        int bkt = (i < E_CHR) ? (cdst[i] >> 8) : (CB_CHR + (sdst[i - E_CHR] >> 8));
        atomicAdd(&h[bkt], 1);
    }
    __syncthreads();
    for (int j = t; j < CB_TOT; j += 256) {
        gh[j * NBLK + blk] = h[j];
        if (h[j]) atomicAdd(&btot[j], h[j]);
    }
}

// single wave scans the 314 bucket totals -> coarse offsets
__global__ void coarse_scan_k(const int* __restrict__ cnt, int* __restrict__ off) {
    int t = threadIdx.x;           // 64 threads
    const int PER = (CB_TOT + 63) / 64;   // 5
    int loc[PER];
    int sum = 0;
    int s = t * PER;
#pragma unroll
    for (int k = 0; k < PER; k++) {
        int i = s + k;
        int v = (i < CB_TOT) ? cnt[i] : 0;
        loc[k] = sum;
        sum += v;
    }
    int inc = sum;
#pragma unroll
    for (int o = 1; o < 64; o <<= 1) {
        int sh = __shfl_up(inc, o, 64);
        if (t >= o) inc += sh;
    }
    int pre = inc - sum;
#pragma unroll
    for (int k = 0; k < PER; k++) {
        int i = s + k;
        if (i < CB_TOT) off[i] = pre + loc[k];
    }
    if (t == 63) off[CB_TOT] = inc;
}

// phase B: per-bucket exclusive scan over the 128 block counts, + coff[bkt]
__global__ __launch_bounds__(NBLK) void block_base_k(int* __restrict__ gh,
                                                     const int* __restrict__ coff) {
    int j = blockIdx.x, t = threadIdx.x;   // 128 threads = 2 waves
    int v = gh[j * NBLK + t];
    int lane = t & 63, wv = t >> 6;
    int inc = v;
#pragma unroll
    for (int o = 1; o < 64; o <<= 1) {
        int sh = __shfl_up(inc, o, 64);
        if (lane >= o) inc += sh;
    }
    __shared__ int ws[2];
    if (lane == 63) ws[wv] = inc;
    __syncthreads();
    int p = inc - v + (wv ? ws[0] : 0);
    gh[j * NBLK + t] = coff[j] + p;
}

// phase C: place edges into pre-reserved dense sub-ranges (LDS cursors, no global atomics)
__global__ __launch_bounds__(256) void scatter2_k(
        const int* __restrict__ cei, const int* __restrict__ sei,
        const int* __restrict__ gh, u32* __restrict__ staging) {
    __shared__ int cur[CB_TOT];
    int blk = blockIdx.x, t = threadIdx.x;
    for (int j = t; j < CB_TOT; j += 256) cur[j] = gh[j * NBLK + blk];
    __syncthreads();
    int s = blk * CHUNK, e = s + CHUNK;
    if (e > E_TOT) e = E_TOT;
    for (int i = s + t; i < e; i += 256) {
        int src, dst, bkt;
        if (i < E_CHR) {
            src = cei[i]; dst = cei[E_CHR + i]; bkt = dst >> 8;
        } else {
            int j2 = i - E_CHR;
            src = sei[j2]; dst = sei[E_SLV + j2]; bkt = CB_CHR + (dst >> 8);
        }
        int p = atomicAdd(&cur[bkt], 1);
        staging[p] = (u32)src | ((u32)(dst & 255) << 17);
    }
}

__device__ inline int block_exscan(int v) {
    int lane = threadIdx.x & 63, wv = threadIdx.x >> 6;
    int inc = v;
#pragma unroll
    for (int o = 1; o < 64; o <<= 1) {
        int t = __shfl_up(inc, o, 64);
        if (lane >= o) inc += t;
    }
    __shared__ int ws[4];
    if (lane == 63) ws[wv] = inc;
    __syncthreads();
    if (threadIdx.x == 0) {
        int c = 0;
#pragma unroll
        for (int k = 0; k < 4; k++) { int t = ws[k]; ws[k] = c; c += t; }
    }
    __syncthreads();
    int r = ws[wv] + inc - v;
    __syncthreads();
    return r;
}

// one block per coarse bucket: counting sort over the 256 node slots
__global__ __launch_bounds__(256) void bucket_sort_k(
        const u32* __restrict__ staging, const int* __restrict__ coff,
        int* __restrict__ off_c, int* __restrict__ off_s,
        int* __restrict__ csr_c, int* __restrict__ csr_s) {
    int b = blockIdx.x, t = threadIdx.x;
    int isS = b >= CB_CHR;
    int base = coff[b], end = coff[b + 1];
    int n = isS ? N_SLV : N_CHR;
    int* off = isS ? off_s : off_c;
    int* csr = isS ? csr_s : csr_c;
    int outBase = isS ? base - E_CHR : base;
    int nodeBase = (isS ? (b - CB_CHR) : b) << 8;
    __shared__ int hist[256];
    __shared__ int cur[256];
    hist[t] = 0;
    __syncthreads();
    for (int i = base + t; i < end; i += 256)
        atomicAdd(&hist[staging[i] >> 17], 1);
    __syncthreads();
    int p = block_exscan(hist[t]);
    int node = nodeBase + t;
    if (node <= n) off[node] = outBase + p;
    cur[t] = p;
    __syncthreads();
    for (int i = base + t; i < end; i += 256) {
        u32 v = staging[i];
        int pos = atomicAdd(&cur[v >> 17], 1);
        csr[outBase + pos] = (int)(v & 0x1FFFFu);
    }
}

// per-graph node ranges from SORTED batch vectors
__global__ void bounds_both_k(const int* __restrict__ cb, const int* __restrict__ sb,
                              int* __restrict__ start_c, int* __restrict__ start_s) {
    int t = threadIdx.x + blockIdx.x * blockDim.x;
    int isS = t >= 320;
    int b = isS ? t - 320 : t;
    if (b > BATCH_B) return;
    const int* batch = isS ? sb : cb;
    int n = isS ? N_SLV : N_CHR;
    int* start = isS ? start_s : start_c;
    if (b == BATCH_B) { start[b] = n; return; }
    int lo = 0, hi = n;
    while (lo < hi) {
        int mid = (lo + hi) >> 1;
        if (batch[mid] < b) lo = mid + 1; else hi = mid;
    }
    start[b] = lo;
}

// ---------------- layer-1 aggregation: bf16 in/out, z = branch, 8 nodes/block ----------------

__global__ __launch_bounds__(256) void agg1_k(
        const u16* __restrict__ Xc, const int* __restrict__ offc, const int* __restrict__ csrc,
        u16* __restrict__ Yc, int nc,
        const u16* __restrict__ Xs, const int* __restrict__ offs, const int* __restrict__ csrs,
        u16* __restrict__ Ys, int ns) {
    int z = blockIdx.z;
    const u32* X32 = (const u32*)(z ? Xs : Xc);
    const int* off = z ? offs : offc;
    const int* csr = z ? csrs : csrc;
    u32* Y32 = (u32*)(z ? Ys : Yc);
    int n = z ? ns : nc;
    int i = blockIdx.x * 8 + (threadIdx.x >> 5);
    if (i >= n) return;
    int fp = threadIdx.x & 31;
    int s = off[i], e2 = off[i + 1];
    float a0 = 0.f, a1 = 0.f;
    int j = s;
    for (; j + 3 < e2; j += 4) {
        u32 v0 = X32[(size_t)csr[j] * 32 + fp];
        u32 v1 = X32[(size_t)csr[j + 1] * 32 + fp];
        u32 v2 = X32[(size_t)csr[j + 2] * 32 + fp];
        u32 v3 = X32[(size_t)csr[j + 3] * 32 + fp];
        a0 += b2f_lo(v0) + b2f_lo(v1) + b2f_lo(v2) + b2f_lo(v3);
        a1 += b2f_hi(v0) + b2f_hi(v1) + b2f_hi(v2) + b2f_hi(v3);
    }
    for (; j < e2; j++) {
        u32 v = X32[(size_t)csr[j] * 32 + fp];
        a0 += b2f_lo(v); a1 += b2f_hi(v);
    }
    Y32[(size_t)i * 32 + fp] = packb(a0, a1);
}

// ---------------- bf16 aggregation F=128, y = ens, z = branch, 8 nodes/block ----------------

template<bool RELU>
__global__ __launch_bounds__(256) void aggb128_k(
        const u16* __restrict__ Hc, const int* __restrict__ offc, const int* __restrict__ csrc,
        u16* __restrict__ Yc, int nc,
        const u16* __restrict__ Hs, const int* __restrict__ offs, const int* __restrict__ csrs,
        u16* __restrict__ Ys, int ns) {
    int z = blockIdx.z, e = blockIdx.y;
    int n = z ? ns : nc;
    const int* off = z ? offs : offc;
    const int* csr = z ? csrs : csrc;
    const u32* He = (const u32*)((z ? Hs : Hc) + (size_t)e * n * DIM);
    u32* Ye = (u32*)((z ? Ys : Yc) + (size_t)e * n * DIM);
    int i = blockIdx.x * 8 + (threadIdx.x >> 5);
    if (i >= n) return;
    int fp = threadIdx.x & 31;
    int s = off[i], e2 = off[i + 1];
    float a0 = 0.f, a1 = 0.f, a2 = 0.f, a3 = 0.f;
    int j = s;
    for (; j + 3 < e2; j += 4) {
        u32x2 v0 = *(const u32x2*)(He + (size_t)csr[j] * 64 + fp * 2);
        u32x2 v1 = *(const u32x2*)(He + (size_t)csr[j + 1] * 64 + fp * 2);
        u32x2 v2 = *(const u32x2*)(He + (size_t)csr[j + 2] * 64 + fp * 2);
        u32x2 v3 = *(const u32x2*)(He + (size_t)csr[j + 3] * 64 + fp * 2);
        a0 += b2f_lo(v0.x) + b2f_lo(v1.x) + b2f_lo(v2.x) + b2f_lo(v3.x);
        a1 += b2f_hi(v0.x) + b2f_hi(v1.x) + b2f_hi(v2.x) + b2f_hi(v3.x);
        a2 += b2f_lo(v0.y) + b2f_lo(v1.y) + b2f_lo(v2.y) + b2f_lo(v3.y);
        a3 += b2f_hi(v0.y) + b2f_hi(v1.y) + b2f_hi(v2.y) + b2f_hi(v3.y);
    }
    for (; j < e2; j++) {
        u32x2 v = *(const u32x2*)(He + (size_t)csr[j] * 64 + fp * 2);
        a0 += b2f_lo(v.x); a1 += b2f_hi(v.x);
        a2 += b2f_lo(v.y); a3 += b2f_hi(v.y);
    }
    if (RELU) {
        a0 = fmaxf(a0, 0.f); a1 = fmaxf(a1, 0.f);
        a2 = fmaxf(a2, 0.f); a3 = fmaxf(a3, 0.f);
    }
    u32x2 o; o.x = packb(a0, a1); o.y = packb(a2, a3);
    *(u32x2*)(Ye + (size_t)i * 64 + fp * 2) = o;
}

// ---------------- bf16 aggregation F=64, y = ens, z = branch, 16 nodes/block ----------------

template<bool RELU>
__global__ __launch_bounds__(256) void aggb64_k(
        const u16* __restrict__ Hc, const int* __restrict__ offc, const int* __restrict__ csrc,
        u16* __restrict__ Yc, int nc,
        const u16* __restrict__ Hs, const int* __restrict__ offs, const int* __restrict__ csrs,
        u16* __restrict__ Ys, int ns) {
    int z = blockIdx.z, e = blockIdx.y;
    int n = z ? ns : nc;
    const int* off = z ? offs : offc;
    const int* csr = z ? csrs : csrc;
    const u32* He = (const u32*)((z ? Hs : Hc) + (size_t)e * n * HALF);
    u32* Ye = (u32*)((z ? Ys : Yc) + (size_t)e * n * HALF);
    int i = blockIdx.x * 16 + (threadIdx.x >> 4);
    if (i >= n) return;
    int fp = threadIdx.x & 15;
    int s = off[i], e2 = off[i + 1];
    float a0 = 0.f, a1 = 0.f, a2 = 0.f, a3 = 0.f;
    int j = s;
    for (; j + 3 < e2; j += 4) {
        u32x2 v0 = *(const u32x2*)(He + (size_t)csr[j] * 32 + fp * 2);
        u32x2 v1 = *(const u32x2*)(He + (size_t)csr[j + 1] * 32 + fp * 2);
        u32x2 v2 = *(const u32x2*)(He + (size_t)csr[j + 2] * 32 + fp * 2);
        u32x2 v3 = *(const u32x2*)(He + (size_t)csr[j + 3] * 32 + fp * 2);
        a0 += b2f_lo(v0.x) + b2f_lo(v1.x) + b2f_lo(v2.x) + b2f_lo(v3.x);
        a1 += b2f_hi(v0.x) + b2f_hi(v1.x) + b2f_hi(v2.x) + b2f_hi(v3.x);
        a2 += b2f_lo(v0.y) + b2f_lo(v1.y) + b2f_lo(v2.y) + b2f_lo(v3.y);
        a3 += b2f_hi(v0.y) + b2f_hi(v1.y) + b2f_hi(v2.y) + b2f_hi(v3.y);
    }
    for (; j < e2; j++) {
        u32x2 v = *(const u32x2*)(He + (size_t)csr[j] * 32 + fp * 2);
        a0 += b2f_lo(v.x); a1 += b2f_hi(v.x);
        a2 += b2f_lo(v.y); a3 += b2f_hi(v.y);
    }
    if (RELU) {
        a0 = fmaxf(a0, 0.f); a1 = fmaxf(a1, 0.f);
        a2 = fmaxf(a2, 0.f); a3 = fmaxf(a3, 0.f);
    }
    u32x2 o; o.x = packb(a0, a1); o.y = packb(a2, a3);
    *(u32x2*)(Ye + (size_t)i * 32 + fp * 2) = o;
}

// ---------------- MFMA GEMM, LDS-staged weights, y = ens, z = branch ----------------
// A[m=lane&15][k=quad*8+j]; B from Wt rows; C/D col=lane&15, row=quad*4+reg.

#define WPAD 8

template<int K, int COLS, bool RELU>
__global__ __launch_bounds__(256) void gemm_mfma_k(
        const u16* __restrict__ Xc, size_t esc, const u16* __restrict__ Wtc,
        u16* __restrict__ Yc, int nc,
        const u16* __restrict__ Xs, size_t ess, const u16* __restrict__ Wts,
        u16* __restrict__ Ys, int ns) {
    __shared__ u16 wlds[COLS * (K + WPAD)];
    const int z = blockIdx.z, e = blockIdx.y;
    const int n = z ? ns : nc;
    const u16* Xe = (z ? Xs : Xc) + (size_t)e * (z ? ess : esc);
    const u16* We = (z ? Wts : Wtc) + (size_t)e * COLS * K;
    u16* Ye = (z ? Ys : Yc) + (size_t)e * (size_t)n * COLS;
    for (int c = threadIdx.x; c < COLS * (K / 8); c += 256) {
        int row = c / (K / 8), seg = c - row * (K / 8);
        *(short8*)(wlds + row * (K + WPAD) + seg * 8) = *(const short8*)(We + (size_t)row * K + seg * 8);
    }
    __syncthreads();
    int wave = threadIdx.x >> 6, lane = threadIdx.x & 63;
    int quad = lane >> 4, nq = lane & 15;
    int m0 = blockIdx.x * 256 + wave * 64;
    if (m0 >= n) return;
    constexpr int NT = COLS / 16, KT = K / 32;
    floatx4 acc[4][NT];
#pragma unroll
    for (int rg = 0; rg < 4; rg++)
#pragma unroll
        for (int t = 0; t < NT; t++) acc[rg][t] = (floatx4)(0.f);
#pragma unroll
    for (int kt = 0; kt < KT; kt++) {
        int k0 = kt * 32 + quad * 8;
        short8 a[4];
#pragma unroll
        for (int rg = 0; rg < 4; rg++) {
            int row = m0 + rg * 16 + nq;
            int rc = row < n ? row : n - 1;
            a[rg] = *(const short8*)(Xe + (size_t)rc * K + k0);
        }
#pragma unroll
        for (int t = 0; t < NT; t++) {
            short8 b = *(const short8*)(wlds + (t * 16 + nq) * (K + WPAD) + k0);
#pragma unroll
            for (int rg = 0; rg < 4; rg++)
                acc[rg][t] = __builtin_amdgcn_mfma_f32_16x16x32_bf16(a[rg], b, acc[rg][t], 0, 0, 0);
        }
    }
    int rbase = quad * 4;
#pragma unroll
    for (int rg = 0; rg < 4; rg++)
#pragma unroll
        for (int t = 0; t < NT; t++)
#pragma unroll
            for (int r = 0; r < 4; r++) {
                int row = m0 + rg * 16 + rbase + r;
                if (row < n) {
                    float v = acc[rg][t][r];
                    if (RELU) v = fmaxf(v, 0.f);
                    Ye[(size_t)row * COLS + t * 16 + nq] = f2b(v);
                }
            }
}

// ---------------- global_add_pool: 4 waves/block, u32 loads, LDS combine ----------------

__global__ __launch_bounds__(256) void pool_b_k(const u16* __restrict__ H,
                                                const int* __restrict__ start,
                                                float* __restrict__ rep, int n, int colOff) {
    int b = blockIdx.x, e = blockIdx.y;
    const u32* He = (const u32*)(H + (size_t)e * n * HALF);
    int t = threadIdx.x;
    int wave = t >> 6, lane = t & 63;
    int fp = lane & 31, rp = lane >> 5;
    int s = start[b], e2 = start[b + 1];
    float a0 = 0.f, a1 = 0.f;
    for (int i = s + wave * 2 + rp; i < e2; i += 8) {
        u32 v = He[(size_t)i * 32 + fp];
        a0 += b2f_lo(v); a1 += b2f_hi(v);
    }
    __shared__ float sm[8][32][2];
    sm[wave * 2 + rp][fp][0] = a0;
    sm[wave * 2 + rp][fp][1] = a1;
    __syncthreads();
    if (t < 64) {
        int f2 = t & 31, half = t >> 5;
        float acc = 0.f;
#pragma unroll
        for (int k = 0; k < 8; k++) acc += sm[k][f2][half];
        rep[b * (2 * ENSN * HALF) + colOff + e * HALF + f2 * 2 + half] = acc;
    }
}

// ---------------- projection heads -> hg[B, 2*ENS*DIM] (fp32) ----------------

__global__ void head_k(const float* __restrict__ rep,
                       const float* __restrict__ cW, const float* __restrict__ cB,
                       const float* __restrict__ sW, const float* __restrict__ sB,
                       float* __restrict__ hg) {
    int b = blockIdx.x;
    int be = blockIdx.y;
    int branch = be / ENSN, e = be % ENSN;
    int c = threadIdx.x;               // 128 threads
    __shared__ float r[HALF];
    const float* repRow = rep + b * (2 * ENSN * HALF) + branch * (ENSN * HALF) + e * HALF;
    if (c < HALF) r[c] = repRow[c];
    __syncthreads();
    const float* W = (branch ? sW : cW) + e * HALF * DIM;
    const float* Bv = (branch ? sB : cB) + e * DIM;
    float acc = Bv[c];
#pragma unroll
    for (int k = 0; k < HALF; k++) acc = fmaf(r[k], W[k * DIM + c], acc);
    hg[b * (2 * ENSN * DIM) + branch * (ENSN * DIM) + e * DIM + c] = fmaxf(acc, 0.f);
}

// ---------------- final MLP ----------------

__global__ void final_k(const float* __restrict__ hg, const float* __restrict__ W1,
                        const float* __restrict__ b1, const float* __restrict__ W2,
                        const float* __restrict__ b2, float* __restrict__ out) {
    int b = blockIdx.x;
    int c = threadIdx.x;               // 128 threads
    const int IN = 2 * ENSN * DIM;     // 768
    __shared__ float row[2 * ENSN * DIM];
    for (int i = c; i < IN; i += DIM) row[i] = hg[b * IN + i];
    __syncthreads();
    float acc = b1[c];
    for (int k = 0; k < IN; k++) acc = fmaf(row[k], W1[k * DIM + c], acc);
    acc = fmaxf(acc, 0.f);
    __shared__ float red[DIM];
    red[c] = acc * W2[c];
    __syncthreads();
    for (int s = DIM / 2; s > 0; s >>= 1) {
        if (c < s) red[c] += red[c + s];
        __syncthreads();
    }
    if (c == 0) out[b] = red[0] + b2[0];
}

// ---------------- host ----------------

extern "C" void kernel_launch(void* const* d_in, const int* in_sizes, int n_in,
                              void* d_out, int out_size, void* d_ws, size_t ws_size,
                              hipStream_t stream) {
    const float* chr_x = (const float*)d_in[0];
    const float* slv_x = (const float*)d_in[1];
    const int* chr_ei = (const int*)d_in[2];
    const int* slv_ei = (const int*)d_in[3];
    const int* chr_batch = (const int*)d_in[4];
    const int* slv_batch = (const int*)d_in[5];
    const float* chr_W0 = (const float*)d_in[6];
    const float* chr_W1 = (const float*)d_in[7];
    const float* chr_W2 = (const float*)d_in[8];
    const float* slv_W0 = (const float*)d_in[9];
    const float* slv_W1 = (const float*)d_in[10];
    const float* slv_W2 = (const float*)d_in[11];
    const float* cfc_W = (const float*)d_in[12];
    const float* cfc_b = (const float*)d_in[13];
    const float* sfc_W = (const float*)d_in[14];
    const float* sfc_b = (const float*)d_in[15];
    const float* fc1_W = (const float*)d_in[16];
    const float* fc1_b = (const float*)d_in[17];
    const float* fc2_W = (const float*)d_in[18];
    const float* fc2_b = (const float*)d_in[19];
    float* out = (float*)d_out;

    char* w = (char*)d_ws;
    auto carve = [&](size_t bytes) {
        void* p = (void*)w;
        w += (bytes + 255) & ~(size_t)255;
        return p;
    };
    int* off_chr = (int*)carve((N_CHR + 1) * sizeof(int));
    int* csr_chr = (int*)carve((size_t)E_CHR * sizeof(int));
    int* off_slv = (int*)carve((N_SLV + 1) * sizeof(int));
    int* csr_slv = (int*)carve((size_t)E_SLV * sizeof(int));
    int* btot    = (int*)carve(CB_TOT * sizeof(int));
    int* coff    = (int*)carve((CB_TOT + 1) * sizeof(int));
    int* gh      = (int*)carve((size_t)CB_TOT * NBLK * sizeof(int));
    u32* staging = (u32*)carve((size_t)E_TOT * sizeof(u32));
    int* start_chr = (int*)carve((BATCH_B + 1) * sizeof(int));
    int* start_slv = (int*)carve((BATCH_B + 1) * sizeof(int));
    u16* cW0t = (u16*)carve((size_t)ENSN * DIM * FEAT * sizeof(u16));
    u16* cW1t = (u16*)carve((size_t)ENSN * DIM * DIM * sizeof(u16));
    u16* cW2t = (u16*)carve((size_t)ENSN * HALF * DIM * sizeof(u16));
    u16* sW0t = (u16*)carve((size_t)ENSN * DIM * FEAT * sizeof(u16));
    u16* sW1t = (u16*)carve((size_t)ENSN * DIM * DIM * sizeof(u16));
    u16* sW2t = (u16*)carve((size_t)ENSN * HALF * DIM * sizeof(u16));
    u16* xb_chr = (u16*)carve((size_t)N_CHR * FEAT * sizeof(u16));
    u16* xb_slv = (u16*)carve((size_t)N_SLV * FEAT * sizeof(u16));
    float* rep = (float*)carve((size_t)BATCH_B * 2 * ENSN * HALF * sizeof(float));
    float* hg  = (float*)carve((size_t)BATCH_B * 2 * ENSN * DIM * sizeof(float));
    u16* aggX_c = (u16*)carve((size_t)N_CHR * FEAT * sizeof(u16));
    u16* bufP_c = (u16*)carve((size_t)ENSN * N_CHR * DIM * sizeof(u16));
    u16* bufQ_c = (u16*)carve((size_t)ENSN * N_CHR * DIM * sizeof(u16));
    // decide if the slv branch gets its own buffers (full z-merge) or reuses chr's
    size_t used = (size_t)(w - (char*)d_ws);
    size_t needS = (((size_t)N_SLV * FEAT * 2 + 255) & ~(size_t)255)
                 + 2 * (((size_t)ENSN * N_SLV * DIM * 2 + 255) & ~(size_t)255);
    bool merged = used + needS <= ws_size;
    u16* aggX_s = merged ? (u16*)carve((size_t)N_SLV * FEAT * sizeof(u16)) : aggX_c;
    u16* bufP_s = merged ? (u16*)carve((size_t)ENSN * N_SLV * DIM * sizeof(u16)) : bufP_c;
    u16* bufQ_s = merged ? (u16*)carve((size_t)ENSN * N_SLV * DIM * sizeof(u16)) : bufQ_c;

    // ---- converts ----
    xconv_k<<<512, 256, 0, stream>>>(chr_x, slv_x, xb_chr, xb_slv);
    wconv_k<<<dim3((FEAT * DIM + 255) / 256, ENSN, 2), 256, 0, stream>>>(chr_W0, slv_W0, cW0t, sW0t, FEAT, DIM);
    wconv_k<<<dim3((DIM * DIM + 255) / 256, ENSN, 2), 256, 0, stream>>>(chr_W1, slv_W1, cW1t, sW1t, DIM, DIM);
    wconv_k<<<dim3((DIM * HALF + 255) / 256, ENSN, 2), 256, 0, stream>>>(chr_W2, slv_W2, cW2t, sW2t, DIM, HALF);

    // ---- CSR build: two-level bucketed counting sort (no global atomic contention) ----
    hipMemsetAsync(btot, 0, CB_TOT * sizeof(int), stream);
    hist_blocks_k<<<NBLK, 256, 0, stream>>>(chr_ei + E_CHR, slv_ei + E_SLV, gh, btot);
    coarse_scan_k<<<1, 64, 0, stream>>>(btot, coff);
    block_base_k<<<CB_TOT, NBLK, 0, stream>>>(gh, coff);
    scatter2_k<<<NBLK, 256, 0, stream>>>(chr_ei, slv_ei, gh, staging);
    bucket_sort_k<<<CB_TOT, 256, 0, stream>>>(staging, coff, off_chr, off_slv, csr_chr, csr_slv);
    bounds_both_k<<<1, 640, 0, stream>>>(chr_batch, slv_batch, start_chr, start_slv);

    const int GX_GEMM_C = (N_CHR + 255) / 256;
    const int GX_GEMM_S = (N_SLV + 255) / 256;

    if (merged) {
        agg1_k<<<dim3((N_CHR + 7) / 8, 1, 2), 256, 0, stream>>>(
            xb_chr, off_chr, csr_chr, aggX_c, N_CHR,
            xb_slv, off_slv, csr_slv, aggX_s, N_SLV);
        gemm_mfma_k<FEAT, DIM, true><<<dim3(GX_GEMM_C, ENSN, 2), 256, 0, stream>>>(
            aggX_c, 0, cW0t, bufP_c, N_CHR, aggX_s, 0, sW0t, bufP_s, N_SLV);
        aggb128_k<false><<<dim3((N_CHR + 7) / 8, ENSN, 2), 256, 0, stream>>>(
            bufP_c, off_chr, csr_chr, bufQ_c, N_CHR,
            bufP_s, off_slv, csr_slv, bufQ_s, N_SLV);
        gemm_mfma_k<DIM, DIM, true><<<dim3(GX_GEMM_C, ENSN, 2), 256, 0, stream>>>(
            bufQ_c, (size_t)N_CHR * DIM, cW1t, bufP_c, N_CHR,
            bufQ_s, (size_t)N_SLV * DIM, sW1t, bufP_s, N_SLV);
        gemm_mfma_k<DIM, HALF, false><<<dim3(GX_GEMM_C, ENSN, 2), 256, 0, stream>>>(
            bufP_c, (size_t)N_CHR * DIM, cW2t, bufQ_c, N_CHR,
            bufP_s, (size_t)N_SLV * DIM, sW2t, bufQ_s, N_SLV);
        aggb64_k<true><<<dim3((N_CHR + 15) / 16, ENSN, 2), 256, 0, stream>>>(
            bufQ_c, off_chr, csr_chr, bufP_c, N_CHR,
            bufQ_s, off_slv, csr_slv, bufP_s, N_SLV);
        pool_b_k<<<dim3(BATCH_B, ENSN), 256, 0, stream>>>(bufP_c, start_chr, rep, N_CHR, 0);
        pool_b_k<<<dim3(BATCH_B, ENSN), 256, 0, stream>>>(bufP_s, start_slv, rep, N_SLV, ENSN * HALF);
    } else {
        // sequential fallback: reuse chr buffers for slv
        agg1_k<<<dim3((N_CHR + 7) / 8, 1, 1), 256, 0, stream>>>(
            xb_chr, off_chr, csr_chr, aggX_c, N_CHR, xb_chr, off_chr, csr_chr, aggX_c, N_CHR);
        gemm_mfma_k<FEAT, DIM, true><<<dim3(GX_GEMM_C, ENSN, 1), 256, 0, stream>>>(
            aggX_c, 0, cW0t, bufP_c, N_CHR, aggX_c, 0, cW0t, bufP_c, N_CHR);
        aggb128_k<false><<<dim3((N_CHR + 7) / 8, ENSN, 1), 256, 0, stream>>>(
            bufP_c, off_chr, csr_chr, bufQ_c, N_CHR, bufP_c, off_chr, csr_chr, bufQ_c, N_CHR);
        gemm_mfma_k<DIM, DIM, true><<<dim3(GX_GEMM_C, ENSN, 1), 256, 0, stream>>>(
            bufQ_c, (size_t)N_CHR * DIM, cW1t, bufP_c, N_CHR,
            bufQ_c, (size_t)N_CHR * DIM, cW1t, bufP_c, N_CHR);
        gemm_mfma_k<DIM, HALF, false><<<dim3(GX_GEMM_C, ENSN, 1), 256, 0, stream>>>(
            bufP_c, (size_t)N_CHR * DIM, cW2t, bufQ_c, N_CHR,
            bufP_c, (size_t)N_CHR * DIM, cW2t, bufQ_c, N_CHR);
        aggb64_k<true><<<dim3((N_CHR + 15) / 16, ENSN, 1), 256, 0, stream>>>(
            bufQ_c, off_chr, csr_chr, bufP_c, N_CHR, bufQ_c, off_chr, csr_chr, bufP_c, N_CHR);
        pool_b_k<<<dim3(BATCH_B, ENSN), 256, 0, stream>>>(bufP_c, start_chr, rep, N_CHR, 0);

        agg1_k<<<dim3((N_SLV + 7) / 8, 1, 1), 256, 0, stream>>>(
            xb_slv, off_slv, csr_slv, aggX_c, N_SLV, xb_slv, off_slv, csr_slv, aggX_c, N_SLV);
        gemm_mfma_k<FEAT, DIM, true><<<dim3(GX_GEMM_S, ENSN, 1), 256, 0, stream>>>(
            aggX_c, 0, sW0t, bufP_c, N_SLV, aggX_c, 0, sW0t, bufP_c, N_SLV);
        aggb128_k<false><<<dim3((N_SLV + 7) / 8, ENSN, 1), 256, 0, stream>>>(
            bufP_c, off_slv, csr_slv, bufQ_c, N_SLV, bufP_c, off_slv, csr_slv, bufQ_c, N_SLV);
        gemm_mfma_k<DIM, DIM, true><<<dim3(GX_GEMM_S, ENSN, 1), 256, 0, stream>>>(
            bufQ_c, (size_t)N_SLV * DIM, sW1t, bufP_c, N_SLV,
            bufQ_c, (size_t)N_SLV * DIM, sW1t, bufP_c, N_SLV);
        gemm_mfma_k<DIM, HALF, false><<<dim3(GX_GEMM_S, ENSN, 1), 256, 0, stream>>>(
            bufP_c, (size_t)N_SLV * DIM, sW2t, bufQ_c, N_SLV,
            bufP_c, (size_t)N_SLV * DIM, sW2t, bufQ_c, N_SLV);
        aggb64_k<true><<<dim3((N_SLV + 15) / 16, ENSN, 1), 256, 0, stream>>>(
            bufQ_c, off_slv, csr_slv, bufP_c, N_SLV, bufQ_c, off_slv, csr_slv, bufP_c, N_SLV);
        pool_b_k<<<dim3(BATCH_B, ENSN), 256, 0, stream>>>(bufP_c, start_slv, rep, N_SLV, ENSN * HALF);
    }

    // ---- heads + final MLP ----
    head_k<<<dim3(BATCH_B, 2 * ENSN), DIM, 0, stream>>>(rep, cfc_W, cfc_b, sfc_W, sfc_b, hg);
    final_k<<<BATCH_B, DIM, 0, stream>>>(hg, fc1_W, fc1_b, fc2_W, fc2_b, out);
}

// Round 7
// 405.368 us; speedup vs baseline: 2.2180x; 1.1261x over previous
//
#include <hip/hip_runtime.h>

#define N_CHR 50000
#define E_CHR 500000
#define N_SLV 30000
#define E_SLV 300000
#define E_TOT (E_CHR + E_SLV)
#define BATCH_B 256
#define FEAT 64
#define DIM 128
#define HALF 64
#define ENSN 3
#define CB_CHR ((N_CHR + 255) / 256)
#define CB_SLV ((N_SLV + 255) / 256)
#define CB_TOT (CB_CHR + CB_SLV)
#define NBLK 128
#define CHUNK ((E_TOT + NBLK - 1) / NBLK)

typedef unsigned int u32;
typedef unsigned short u16;
typedef __attribute__((ext_vector_type(8))) short short8;
typedef __attribute__((ext_vector_type(4))) float floatx4;
typedef __attribute__((ext_vector_type(4))) unsigned int u32x4;

// ---------------- bf16 helpers (round-to-nearest-even) ----------------

__device__ inline u16 f2b(float f) {
    u32 u = __builtin_bit_cast(u32, f);
    u += 0x7FFFu + ((u >> 16) & 1u);
    return (u16)(u >> 16);
}
__device__ inline float b2f_lo(u32 v) { return __builtin_bit_cast(float, v << 16); }
__device__ inline float b2f_hi(u32 v) { return __builtin_bit_cast(float, v & 0xFFFF0000u); }
__device__ inline u32 packb(float a, float b) { return (u32)f2b(a) | ((u32)f2b(b) << 16); }

__device__ inline void acc8(float* a, u32x4 v) {
    a[0] += b2f_lo(v.x); a[1] += b2f_hi(v.x);
    a[2] += b2f_lo(v.y); a[3] += b2f_hi(v.y);
    a[4] += b2f_lo(v.z); a[5] += b2f_hi(v.z);
    a[6] += b2f_lo(v.w); a[7] += b2f_hi(v.w);
}

// ---------------- input convert: fp32 -> bf16, both branches ----------------

__global__ void xconv_k(const float* __restrict__ xc, const float* __restrict__ xs,
                        u16* __restrict__ oc, u16* __restrict__ os) {
    const int nc = N_CHR * FEAT, ns = N_SLV * FEAT;
    int i = blockIdx.x * blockDim.x + threadIdx.x;
    int stride = gridDim.x * blockDim.x;
    for (; i < nc + ns; i += stride) {
        if (i < nc) oc[i] = f2b(xc[i]);
        else os[i - nc] = f2b(xs[i - nc]);
    }
}

// ---------------- all 6 weight convert+transpose in one launch ----------------
// W[E][K][N] f32 -> Wt[E][N][K] bf16 ; z selects tensor

__global__ void wconv6_k(const float* __restrict__ cW0, const float* __restrict__ cW1,
                         const float* __restrict__ cW2, const float* __restrict__ sW0,
                         const float* __restrict__ sW1, const float* __restrict__ sW2,
                         u16* __restrict__ cW0t, u16* __restrict__ cW1t, u16* __restrict__ cW2t,
                         u16* __restrict__ sW0t, u16* __restrict__ sW1t, u16* __restrict__ sW2t) {
    int z = blockIdx.z, e = blockIdx.y;
    const float* W; u16* Wt; int K, N;
    switch (z) {
        case 0: W = cW0; Wt = cW0t; K = FEAT; N = DIM;  break;
        case 1: W = cW1; Wt = cW1t; K = DIM;  N = DIM;  break;
        case 2: W = cW2; Wt = cW2t; K = DIM;  N = HALF; break;
        case 3: W = sW0; Wt = sW0t; K = FEAT; N = DIM;  break;
        case 4: W = sW1; Wt = sW1t; K = DIM;  N = DIM;  break;
        default: W = sW2; Wt = sW2t; K = DIM; N = HALF; break;
    }
    int idx = blockIdx.x * 256 + threadIdx.x;
    if (idx >= K * N) return;
    int k = idx / N, nn = idx - k * N;
    Wt[((size_t)e * N + nn) * K + k] = f2b(W[(size_t)e * K * N + idx]);
}

// ---------------- CSR build: two-level bucketed counting sort ----------------
// pack: src | ((dst & 255) << 17)

__global__ __launch_bounds__(256) void hist_blocks_k(
        const int* __restrict__ cdst, const int* __restrict__ sdst,
        int* __restrict__ gh, int* __restrict__ btot) {
    __shared__ int h[CB_TOT];
    int blk = blockIdx.x, t = threadIdx.x;
    for (int i = t; i < CB_TOT; i += 256) h[i] = 0;
    __syncthreads();
    int s = blk * CHUNK, e = s + CHUNK;
    if (e > E_TOT) e = E_TOT;
    for (int i = s + t; i < e; i += 256) {
        int bkt = (i < E_CHR) ? (cdst[i] >> 8) : (CB_CHR + (sdst[i - E_CHR] >> 8));
        atomicAdd(&h[bkt], 1);
    }
    __syncthreads();
    for (int j = t; j < CB_TOT; j += 256) {
        gh[j * NBLK + blk] = h[j];
        if (h[j]) atomicAdd(&btot[j], h[j]);
    }
}

__global__ void coarse_scan_k(const int* __restrict__ cnt, int* __restrict__ off) {
    int t = threadIdx.x;           // 64 threads
    const int PER = (CB_TOT + 63) / 64;
    int loc[PER];
    int sum = 0;
    int s = t * PER;
#pragma unroll
    for (int k = 0; k < PER; k++) {
        int i = s + k;
        int v = (i < CB_TOT) ? cnt[i] : 0;
        loc[k] = sum;
        sum += v;
    }
    int inc = sum;
#pragma unroll
    for (int o = 1; o < 64; o <<= 1) {
        int sh = __shfl_up(inc, o, 64);
        if (t >= o) inc += sh;
    }
    int pre = inc - sum;
#pragma unroll
    for (int k = 0; k < PER; k++) {
        int i = s + k;
        if (i < CB_TOT) off[i] = pre + loc[k];
    }
    if (t == 63) off[CB_TOT] = inc;
}

__global__ __launch_bounds__(NBLK) void block_base_k(int* __restrict__ gh,
                                                     const int* __restrict__ coff) {
    int j = blockIdx.x, t = threadIdx.x;
    int v = gh[j * NBLK + t];
    int lane = t & 63, wv = t >> 6;
    int inc = v;
#pragma unroll
    for (int o = 1; o < 64; o <<= 1) {
        int sh = __shfl_up(inc, o, 64);
        if (lane >= o) inc += sh;
    }
    __shared__ int ws[2];
    if (lane == 63) ws[wv] = inc;
    __syncthreads();
    int p = inc - v + (wv ? ws[0] : 0);
    gh[j * NBLK + t] = coff[j] + p;
}

__global__ __launch_bounds__(256) void scatter2_k(
        const int* __restrict__ cei, const int* __restrict__ sei,
        const int* __restrict__ gh, u32* __restrict__ staging) {
    __shared__ int cur[CB_TOT];
    int blk = blockIdx.x, t = threadIdx.x;
    for (int j = t; j < CB_TOT; j += 256) cur[j] = gh[j * NBLK + blk];
    __syncthreads();
    int s = blk * CHUNK, e = s + CHUNK;
    if (e > E_TOT) e = E_TOT;
    for (int i = s + t; i < e; i += 256) {
        int src, dst, bkt;
        if (i < E_CHR) {
            src = cei[i]; dst = cei[E_CHR + i]; bkt = dst >> 8;
        } else {
            int j2 = i - E_CHR;
            src = sei[j2]; dst = sei[E_SLV + j2]; bkt = CB_CHR + (dst >> 8);
        }
        int p = atomicAdd(&cur[bkt], 1);
        staging[p] = (u32)src | ((u32)(dst & 255) << 17);
    }
}

__device__ inline int block_exscan(int v) {
    int lane = threadIdx.x & 63, wv = threadIdx.x >> 6;
    int inc = v;
#pragma unroll
    for (int o = 1; o < 64; o <<= 1) {
        int t = __shfl_up(inc, o, 64);
        if (lane >= o) inc += t;
    }
    __shared__ int ws[4];
    if (lane == 63) ws[wv] = inc;
    __syncthreads();
    if (threadIdx.x == 0) {
        int c = 0;
#pragma unroll
        for (int k = 0; k < 4; k++) { int t = ws[k]; ws[k] = c; c += t; }
    }
    __syncthreads();
    int r = ws[wv] + inc - v;
    __syncthreads();
    return r;
}

__global__ __launch_bounds__(256) void bucket_sort_k(
        const u32* __restrict__ staging, const int* __restrict__ coff,
        int* __restrict__ off_c, int* __restrict__ off_s,
        int* __restrict__ csr_c, int* __restrict__ csr_s) {
    int b = blockIdx.x, t = threadIdx.x;
    int isS = b >= CB_CHR;
    int base = coff[b], end = coff[b + 1];
    int n = isS ? N_SLV : N_CHR;
    int* off = isS ? off_s : off_c;
    int* csr = isS ? csr_s : csr_c;
    int outBase = isS ? base - E_CHR : base;
    int nodeBase = (isS ? (b - CB_CHR) : b) << 8;
    __shared__ int hist[256];
    __shared__ int cur[256];
    hist[t] = 0;
    __syncthreads();
    for (int i = base + t; i < end; i += 256)
        atomicAdd(&hist[staging[i] >> 17], 1);
    __syncthreads();
    int p = block_exscan(hist[t]);
    int node = nodeBase + t;
    if (node <= n) off[node] = outBase + p;
    cur[t] = p;
    __syncthreads();
    for (int i = base + t; i < end; i += 256) {
        u32 v = staging[i];
        int pos = atomicAdd(&cur[v >> 17], 1);
        csr[outBase + pos] = (int)(v & 0x1FFFFu);
    }
}

// ---------------- layer-1 aggregation: bf16, u32x4 loads, 32 nodes/block ----------------

__global__ __launch_bounds__(256) void agg1_k(
        const u16* __restrict__ Xc, const int* __restrict__ offc, const int* __restrict__ csrc,
        u16* __restrict__ Yc, int nc,
        const u16* __restrict__ Xs, const int* __restrict__ offs, const int* __restrict__ csrs,
        u16* __restrict__ Ys, int ns) {
    int z = blockIdx.z;
    const u32x4* X4 = (const u32x4*)(z ? Xs : Xc);
    const int* off = z ? offs : offc;
    const int* csr = z ? csrs : csrc;
    u32x4* Y4 = (u32x4*)(z ? Ys : Yc);
    int n = z ? ns : nc;
    int i = blockIdx.x * 32 + (threadIdx.x >> 3);
    if (i >= n) return;
    int l8 = threadIdx.x & 7;          // FEAT=64 -> 8 chunks of 16B
    int s = off[i], e2 = off[i + 1];
    float a[8] = {0.f, 0.f, 0.f, 0.f, 0.f, 0.f, 0.f, 0.f};
    int j = s;
    for (; j + 1 < e2; j += 2) {
        u32x4 v0 = X4[(size_t)csr[j] * 8 + l8];
        u32x4 v1 = X4[(size_t)csr[j + 1] * 8 + l8];
        acc8(a, v0); acc8(a, v1);
    }
    if (j < e2) acc8(a, X4[(size_t)csr[j] * 8 + l8]);
    u32x4 o;
    o.x = packb(a[0], a[1]); o.y = packb(a[2], a[3]);
    o.z = packb(a[4], a[5]); o.w = packb(a[6], a[7]);
    Y4[(size_t)i * 8 + l8] = o;
}

// ---------------- layer-2 aggregation F=128: u32x4 loads, 16 nodes/block ----------------

__global__ __launch_bounds__(256) void aggb128_k(
        const u16* __restrict__ Hc, const int* __restrict__ offc, const int* __restrict__ csrc,
        u16* __restrict__ Yc, int nc,
        const u16* __restrict__ Hs, const int* __restrict__ offs, const int* __restrict__ csrs,
        u16* __restrict__ Ys, int ns) {
    int z = blockIdx.z, e = blockIdx.y;
    int n = z ? ns : nc;
    const int* off = z ? offs : offc;
    const int* csr = z ? csrs : csrc;
    const u32x4* He = (const u32x4*)((z ? Hs : Hc) + (size_t)e * n * DIM);   // 16 chunks/row
    u32x4* Ye = (u32x4*)((z ? Ys : Yc) + (size_t)e * n * DIM);
    int i = blockIdx.x * 16 + (threadIdx.x >> 4);
    if (i >= n) return;
    int l16 = threadIdx.x & 15;
    int s = off[i], e2 = off[i + 1];
    float a[8] = {0.f, 0.f, 0.f, 0.f, 0.f, 0.f, 0.f, 0.f};
    int j = s;
    for (; j + 1 < e2; j += 2) {
        u32x4 v0 = He[(size_t)csr[j] * 16 + l16];
        u32x4 v1 = He[(size_t)csr[j + 1] * 16 + l16];
        acc8(a, v0); acc8(a, v1);
    }
    if (j < e2) acc8(a, He[(size_t)csr[j] * 16 + l16]);
    u32x4 o;
    o.x = packb(a[0], a[1]); o.y = packb(a[2], a[3]);
    o.z = packb(a[4], a[5]); o.w = packb(a[6], a[7]);
    Ye[(size_t)i * 16 + l16] = o;
}

// ---------------- GEMM1: h1 = relu(aggX @ W0), LDS weights, 256 rows/block ----------------

#define WPAD 8

template<int K, int COLS, bool RELU>
__global__ __launch_bounds__(256) void gemm_mfma_k(
        const u16* __restrict__ Xc, size_t esc, const u16* __restrict__ Wtc,
        u16* __restrict__ Yc, int nc,
        const u16* __restrict__ Xs, size_t ess, const u16* __restrict__ Wts,
        u16* __restrict__ Ys, int ns) {
    __shared__ u16 wlds[COLS * (K + WPAD)];
    const int z = blockIdx.z, e = blockIdx.y;
    const int n = z ? ns : nc;
    const u16* Xe = (z ? Xs : Xc) + (size_t)e * (z ? ess : esc);
    const u16* We = (z ? Wts : Wtc) + (size_t)e * COLS * K;
    u16* Ye = (z ? Ys : Yc) + (size_t)e * (size_t)n * COLS;
    for (int c = threadIdx.x; c < COLS * (K / 8); c += 256) {
        int row = c / (K / 8), seg = c - row * (K / 8);
        *(short8*)(wlds + row * (K + WPAD) + seg * 8) = *(const short8*)(We + (size_t)row * K + seg * 8);
    }
    __syncthreads();
    int wave = threadIdx.x >> 6, lane = threadIdx.x & 63;
    int quad = lane >> 4, nq = lane & 15;
    int m0 = blockIdx.x * 256 + wave * 64;
    if (m0 >= n) return;
    constexpr int NT = COLS / 16, KT = K / 32;
    floatx4 acc[4][NT];
#pragma unroll
    for (int rg = 0; rg < 4; rg++)
#pragma unroll
        for (int t = 0; t < NT; t++) acc[rg][t] = (floatx4)(0.f);
#pragma unroll
    for (int kt = 0; kt < KT; kt++) {
        int k0 = kt * 32 + quad * 8;
        short8 a[4];
#pragma unroll
        for (int rg = 0; rg < 4; rg++) {
            int row = m0 + rg * 16 + nq;
            int rc = row < n ? row : n - 1;
            a[rg] = *(const short8*)(Xe + (size_t)rc * K + k0);
        }
#pragma unroll
        for (int t = 0; t < NT; t++) {
            short8 b = *(const short8*)(wlds + (t * 16 + nq) * (K + WPAD) + k0);
#pragma unroll
            for (int rg = 0; rg < 4; rg++)
                acc[rg][t] = __builtin_amdgcn_mfma_f32_16x16x32_bf16(a[rg], b, acc[rg][t], 0, 0, 0);
        }
    }
    int rbase = quad * 4;
#pragma unroll
    for (int rg = 0; rg < 4; rg++)
#pragma unroll
        for (int t = 0; t < NT; t++)
#pragma unroll
            for (int r = 0; r < 4; r++) {
                int row = m0 + rg * 16 + rbase + r;
                if (row < n) {
                    float v = acc[rg][t][r];
                    if (RELU) v = fmaxf(v, 0.f);
                    Ye[(size_t)row * COLS + t * 16 + nq] = f2b(v);
                }
            }
}

// ---------------- fused GEMM2+GEMM3: p3 = (relu(A@W1)) @ W2 ----------------
// 128 rows/block, 4 waves x 32 rows. h2 round-trips through 16B-chunk XOR-swizzled
// LDS (pitch DIM, no pad): chunk_phys = chunk_log ^ (row & 15) -> 2-way (free) on
// all b128 reads. W2 staged into W1's region after the h2 barrier (re-read hits L2:
// W2t total 48KB). LDS = 32KB + 32KB = 64KB -> 2 blocks/CU.

__global__ __launch_bounds__(256) void gemm23_k(
        const u16* __restrict__ Xc, const u16* __restrict__ W1c, const u16* __restrict__ W2c,
        u16* __restrict__ Yc, int nc,
        const u16* __restrict__ Xs, const u16* __restrict__ W1s, const u16* __restrict__ W2s,
        u16* __restrict__ Ys, int ns) {
    __shared__ u16 wlds[DIM * DIM];        // 32 KB: W1 then W2 (swizzled)
    __shared__ u16 hlds[4 * 32 * DIM];     // 32 KB: per-wave h2 tiles (swizzled)
    const int z = blockIdx.z, e = blockIdx.y;
    const int n = z ? ns : nc;
    const u16* Xe = (z ? Xs : Xc) + (size_t)e * (size_t)n * DIM;
    const u16* W1 = (z ? W1s : W1c) + (size_t)e * DIM * DIM;
    const u16* W2 = (z ? W2s : W2c) + (size_t)e * HALF * DIM;
    u16* Ye = (z ? Ys : Yc) + (size_t)e * (size_t)n * HALF;
    // stage W1 swizzled
    for (int c = threadIdx.x; c < DIM * (DIM / 8); c += 256) {
        int row = c >> 4, seg = c & 15;
        *(short8*)(wlds + row * DIM + ((seg ^ (row & 15)) << 3)) =
            *(const short8*)(W1 + (size_t)row * DIM + (seg << 3));
    }
    __syncthreads();
    int wave = threadIdx.x >> 6, lane = threadIdx.x & 63;
    int quad = lane >> 4, nq = lane & 15;
    int m0 = blockIdx.x * 128 + wave * 32;     // no early return: barriers below
    // ---- GEMM2: h2 = relu(A @ W1) ----
    floatx4 acc[2][8];
#pragma unroll
    for (int rg = 0; rg < 2; rg++)
#pragma unroll
        for (int t = 0; t < 8; t++) acc[rg][t] = (floatx4)(0.f);
#pragma unroll
    for (int kt = 0; kt < 4; kt++) {
        int k0 = kt * 32 + quad * 8;
        short8 a[2];
#pragma unroll
        for (int rg = 0; rg < 2; rg++) {
            int row = m0 + rg * 16 + nq;
            int rc = row < n ? row : (n - 1);
            a[rg] = *(const short8*)(Xe + (size_t)rc * DIM + k0);
        }
#pragma unroll
        for (int t = 0; t < 8; t++) {
            int rb = t * 16 + nq;
            short8 b = *(const short8*)(wlds + rb * DIM + ((((kt << 2) + quad) ^ nq) << 3));
#pragma unroll
            for (int rg = 0; rg < 2; rg++)
                acc[rg][t] = __builtin_amdgcn_mfma_f32_16x16x32_bf16(a[rg], b, acc[rg][t], 0, 0, 0);
        }
    }
    // h2 (C-layout) -> swizzled LDS as bf16, relu
    u16* hw = hlds + wave * 32 * DIM;
#pragma unroll
    for (int rg = 0; rg < 2; rg++)
#pragma unroll
        for (int t = 0; t < 8; t++)
#pragma unroll
            for (int r = 0; r < 4; r++) {
                int rl = rg * 16 + quad * 4 + r;
                int col = t * 16 + nq;
                hw[rl * DIM + (((col >> 3) ^ (rl & 15)) << 3) + (col & 7)] =
                    f2b(fmaxf(acc[rg][t][r], 0.f));
            }
    __syncthreads();
    // stage W2 (64 x 128) into wlds rows 0..63 (swizzled)
    for (int c = threadIdx.x; c < HALF * (DIM / 8); c += 256) {
        int row = c >> 4, seg = c & 15;
        *(short8*)(wlds + row * DIM + ((seg ^ (row & 15)) << 3)) =
            *(const short8*)(W2 + (size_t)row * DIM + (seg << 3));
    }
    __syncthreads();
    // ---- GEMM3: p3 = h2 @ W2 ----
    floatx4 acc2[2][4];
#pragma unroll
    for (int rg = 0; rg < 2; rg++)
#pragma unroll
        for (int t = 0; t < 4; t++) acc2[rg][t] = (floatx4)(0.f);
#pragma unroll
    for (int kt = 0; kt < 4; kt++) {
        int k0q = (kt << 2) + quad;
        short8 a[2];
#pragma unroll
        for (int rg = 0; rg < 2; rg++) {
            int rl = rg * 16 + nq;
            a[rg] = *(const short8*)(hw + rl * DIM + ((k0q ^ (rl & 15)) << 3));
        }
#pragma unroll
        for (int t = 0; t < 4; t++) {
            int rb = t * 16 + nq;
            short8 b = *(const short8*)(wlds + rb * DIM + ((k0q ^ nq) << 3));
#pragma unroll
            for (int rg = 0; rg < 2; rg++)
                acc2[rg][t] = __builtin_amdgcn_mfma_f32_16x16x32_bf16(a[rg], b, acc2[rg][t], 0, 0, 0);
        }
    }
#pragma unroll
    for (int rg = 0; rg < 2; rg++)
#pragma unroll
        for (int t = 0; t < 4; t++)
#pragma unroll
            for (int r = 0; r < 4; r++) {
                int row = m0 + rg * 16 + quad * 4 + r;
                if (row < n) Ye[(size_t)row * HALF + t * 16 + nq] = f2b(acc2[rg][t][r]);
            }
}

// ---------------- fused layer-3 agg + relu + global_add_pool ----------------
// h3 = relu(agg(p3)) is consumed ONLY by pool: never materialized. 32 nodes/block,
// 8 lanes/node u32x4; per-block LDS tile then per-graph run-length reduce + atomics.

__global__ __launch_bounds__(256) void agg64pool_k(
        const u16* __restrict__ Pc, const int* __restrict__ offc, const int* __restrict__ csrc,
        const int* __restrict__ batc, int nc,
        const u16* __restrict__ Ps, const int* __restrict__ offs, const int* __restrict__ csrs,
        const int* __restrict__ bats, int ns,
        float* __restrict__ rep) {
    int z = blockIdx.z, e = blockIdx.y;
    int n = z ? ns : nc;
    const int* off = z ? offs : offc;
    const int* csr = z ? csrs : csrc;
    const int* batch = z ? bats : batc;
    const u32x4* He = (const u32x4*)((z ? Ps : Pc) + (size_t)e * n * HALF);  // 8 chunks/row
    int i0 = blockIdx.x * 32;
    int nl = threadIdx.x >> 3, l8 = threadIdx.x & 7;
    int i = i0 + nl;
    float a[8] = {0.f, 0.f, 0.f, 0.f, 0.f, 0.f, 0.f, 0.f};
    if (i < n) {
        int s = off[i], e2 = off[i + 1];
        int j = s;
        for (; j + 1 < e2; j += 2) {
            u32x4 v0 = He[(size_t)csr[j] * 8 + l8];
            u32x4 v1 = He[(size_t)csr[j + 1] * 8 + l8];
            acc8(a, v0); acc8(a, v1);
        }
        if (j < e2) acc8(a, He[(size_t)csr[j] * 8 + l8]);
    }
    __shared__ float sm[32][64];
    __shared__ int gb[32];
#pragma unroll
    for (int k = 0; k < 8; k++) sm[nl][l8 * 8 + k] = fmaxf(a[k], 0.f);
    if (threadIdx.x < 32) gb[threadIdx.x] = (i0 + (int)threadIdx.x < n) ? batch[i0 + threadIdx.x] : -1;
    __syncthreads();
    if (threadIdx.x < 64) {
        int f = threadIdx.x;
        int colbase = z * (ENSN * HALF) + e * HALF + f;
        float acc = 0.f;
        int g = -2;
        for (int k = 0; k < 32; k++) {
            int gg = gb[k];
            if (gg != g) {
                if (g >= 0) atomicAdd(&rep[g * (2 * ENSN * HALF) + colbase], acc);
                acc = 0.f;
                g = gg;
            }
            if (gg >= 0) acc += sm[k][f];
        }
        if (g >= 0) atomicAdd(&rep[g * (2 * ENSN * HALF) + colbase], acc);
    }
}

// ---------------- fused heads + final MLP: one block per graph ----------------

__global__ __launch_bounds__(256) void headfinal_k(
        const float* __restrict__ rep,
        const float* __restrict__ cW, const float* __restrict__ cB,
        const float* __restrict__ sW, const float* __restrict__ sB,
        const float* __restrict__ W1, const float* __restrict__ b1,
        const float* __restrict__ W2, const float* __restrict__ b2,
        float* __restrict__ out) {
    int b = blockIdx.x, t = threadIdx.x;
    __shared__ float r[2 * ENSN * HALF];       // 384
    __shared__ float hg[2 * ENSN * DIM];       // 768
    __shared__ float red[DIM];
    for (int i = t; i < 2 * ENSN * HALF; i += 256) r[i] = rep[b * (2 * ENSN * HALF) + i];
    __syncthreads();
    for (int o = t; o < 2 * ENSN * DIM; o += 256) {
        int head = o >> 7, c = o & 127;
        int branch = head / ENSN, e = head - branch * ENSN;
        const float* W = (branch ? sW : cW) + (size_t)e * HALF * DIM;
        const float* rr = r + branch * (ENSN * HALF) + e * HALF;
        float acc = (branch ? sB : cB)[e * DIM + c];
#pragma unroll
        for (int k = 0; k < HALF; k++) acc = fmaf(rr[k], W[k * DIM + c], acc);
        hg[o] = fmaxf(acc, 0.f);
    }
    __syncthreads();
    if (t < DIM) {
        float acc = b1[t];
        for (int k = 0; k < 2 * ENSN * DIM; k++) acc = fmaf(hg[k], W1[k * DIM + t], acc);
        red[t] = fmaxf(acc, 0.f) * W2[t];
    }
    __syncthreads();
    if (t < 64) {
        float v = red[t] + red[t + 64];
#pragma unroll
        for (int o = 32; o > 0; o >>= 1) v += __shfl_down(v, o, 64);
        if (t == 0) out[b] = v + b2[0];
    }
}

// ---------------- host ----------------

extern "C" void kernel_launch(void* const* d_in, const int* in_sizes, int n_in,
                              void* d_out, int out_size, void* d_ws, size_t ws_size,
                              hipStream_t stream) {
    const float* chr_x = (const float*)d_in[0];
    const float* slv_x = (const float*)d_in[1];
    const int* chr_ei = (const int*)d_in[2];
    const int* slv_ei = (const int*)d_in[3];
    const int* chr_batch = (const int*)d_in[4];
    const int* slv_batch = (const int*)d_in[5];
    const float* chr_W0 = (const float*)d_in[6];
    const float* chr_W1 = (const float*)d_in[7];
    const float* chr_W2 = (const float*)d_in[8];
    const float* slv_W0 = (const float*)d_in[9];
    const float* slv_W1 = (const float*)d_in[10];
    const float* slv_W2 = (const float*)d_in[11];
    const float* cfc_W = (const float*)d_in[12];
    const float* cfc_b = (const float*)d_in[13];
    const float* sfc_W = (const float*)d_in[14];
    const float* sfc_b = (const float*)d_in[15];
    const float* fc1_W = (const float*)d_in[16];
    const float* fc1_b = (const float*)d_in[17];
    const float* fc2_W = (const float*)d_in[18];
    const float* fc2_b = (const float*)d_in[19];
    float* out = (float*)d_out;

    char* w = (char*)d_ws;
    auto carve = [&](size_t bytes) {
        void* p = (void*)w;
        w += (bytes + 255) & ~(size_t)255;
        return p;
    };
    int* off_chr = (int*)carve((N_CHR + 1) * sizeof(int));
    int* csr_chr = (int*)carve((size_t)E_CHR * sizeof(int));
    int* off_slv = (int*)carve((N_SLV + 1) * sizeof(int));
    int* csr_slv = (int*)carve((size_t)E_SLV * sizeof(int));
    int* btot    = (int*)carve(CB_TOT * sizeof(int));
    int* coff    = (int*)carve((CB_TOT + 1) * sizeof(int));
    int* gh      = (int*)carve((size_t)CB_TOT * NBLK * sizeof(int));
    u32* staging = (u32*)carve((size_t)E_TOT * sizeof(u32));
    u16* cW0t = (u16*)carve((size_t)ENSN * DIM * FEAT * sizeof(u16));
    u16* cW1t = (u16*)carve((size_t)ENSN * DIM * DIM * sizeof(u16));
    u16* cW2t = (u16*)carve((size_t)ENSN * HALF * DIM * sizeof(u16));
    u16* sW0t = (u16*)carve((size_t)ENSN * DIM * FEAT * sizeof(u16));
    u16* sW1t = (u16*)carve((size_t)ENSN * DIM * DIM * sizeof(u16));
    u16* sW2t = (u16*)carve((size_t)ENSN * HALF * DIM * sizeof(u16));
    u16* xb_chr = (u16*)carve((size_t)N_CHR * FEAT * sizeof(u16));
    u16* xb_slv = (u16*)carve((size_t)N_SLV * FEAT * sizeof(u16));
    float* rep = (float*)carve((size_t)BATCH_B * 2 * ENSN * HALF * sizeof(float));
    u16* aggX_c = (u16*)carve((size_t)N_CHR * FEAT * sizeof(u16));
    u16* bufP_c = (u16*)carve((size_t)ENSN * N_CHR * DIM * sizeof(u16));   // h1, later p3
    u16* bufQ_c = (u16*)carve((size_t)ENSN * N_CHR * DIM * sizeof(u16));   // agg(h1)
    u16* aggX_s = (u16*)carve((size_t)N_SLV * FEAT * sizeof(u16));
    u16* bufP_s = (u16*)carve((size_t)ENSN * N_SLV * DIM * sizeof(u16));
    u16* bufQ_s = (u16*)carve((size_t)ENSN * N_SLV * DIM * sizeof(u16));

    // ---- converts ----
    xconv_k<<<512, 256, 0, stream>>>(chr_x, slv_x, xb_chr, xb_slv);
    wconv6_k<<<dim3(64, ENSN, 6), 256, 0, stream>>>(chr_W0, chr_W1, chr_W2,
                                                    slv_W0, slv_W1, slv_W2,
                                                    cW0t, cW1t, cW2t, sW0t, sW1t, sW2t);

    // ---- CSR build ----
    hipMemsetAsync(btot, 0, CB_TOT * sizeof(int), stream);
    hist_blocks_k<<<NBLK, 256, 0, stream>>>(chr_ei + E_CHR, slv_ei + E_SLV, gh, btot);
    coarse_scan_k<<<1, 64, 0, stream>>>(btot, coff);
    block_base_k<<<CB_TOT, NBLK, 0, stream>>>(gh, coff);
    scatter2_k<<<NBLK, 256, 0, stream>>>(chr_ei, slv_ei, gh, staging);
    bucket_sort_k<<<CB_TOT, 256, 0, stream>>>(staging, coff, off_chr, off_slv, csr_chr, csr_slv);

    hipMemsetAsync(rep, 0, (size_t)BATCH_B * 2 * ENSN * HALF * sizeof(float), stream);

    // ---- branches (chr+slv via z, ensembles via y) ----
    agg1_k<<<dim3((N_CHR + 31) / 32, 1, 2), 256, 0, stream>>>(
        xb_chr, off_chr, csr_chr, aggX_c, N_CHR,
        xb_slv, off_slv, csr_slv, aggX_s, N_SLV);
    gemm_mfma_k<FEAT, DIM, true><<<dim3((N_CHR + 255) / 256, ENSN, 2), 256, 0, stream>>>(
        aggX_c, 0, cW0t, bufP_c, N_CHR, aggX_s, 0, sW0t, bufP_s, N_SLV);
    aggb128_k<<<dim3((N_CHR + 15) / 16, ENSN, 2), 256, 0, stream>>>(
        bufP_c, off_chr, csr_chr, bufQ_c, N_CHR,
        bufP_s, off_slv, csr_slv, bufQ_s, N_SLV);
    gemm23_k<<<dim3((N_CHR + 127) / 128, ENSN, 2), 256, 0, stream>>>(
        bufQ_c, cW1t, cW2t, bufP_c, N_CHR,
        bufQ_s, sW1t, sW2t, bufP_s, N_SLV);                  // p3 overwrites h1
    agg64pool_k<<<dim3((N_CHR + 31) / 32, ENSN, 2), 256, 0, stream>>>(
        bufP_c, off_chr, csr_chr, chr_batch, N_CHR,
        bufP_s, off_slv, csr_slv, slv_batch, N_SLV, rep);

    // ---- heads + final MLP ----
    headfinal_k<<<BATCH_B, 256, 0, stream>>>(rep, cfc_W, cfc_b, sfc_W, sfc_b,
                                             fc1_W, fc1_b, fc2_W, fc2_b, out);
}